// Round 7
// baseline (744.190 us; speedup 1.0000x reference)
//
#include <hip/hip_runtime.h>
#include <hip/hip_bf16.h>
#include <math.h>

#define Nn 10000
#define Ee 160000
#define ET 170000   // Ee + Nn (self loops)
#define LL 6

typedef short v8s __attribute__((ext_vector_type(8)));
typedef float v4f __attribute__((ext_vector_type(4)));

__device__ __forceinline__ unsigned short f2bf(float v) {
    unsigned int b = __float_as_uint(v);
    b += 0x7fffu + ((b >> 16) & 1u);   // RNE
    return (unsigned short)(b >> 16);
}

// ---------------- node embedding: h = x @ node_w + node_b ----------------
__global__ void k_node_embed(const float* __restrict__ x, const float* __restrict__ nw,
                             const float* __restrict__ nb, float* __restrict__ h) {
    int idx = blockIdx.x * 256 + threadIdx.x;
    if (idx >= Nn * 128) return;
    int n = idx >> 7, c = idx & 127;
    const float* xr = x + (size_t)n * 8;
    float acc = nb[c];
#pragma unroll
    for (int k = 0; k < 8; k++) acc += xr[k] * nw[k * 128 + c];
    h[idx] = acc;
}

// ---------------- small precompute: E1[128][8] = {M1[0..3][k], d1[k], 0,0,0} ----------------
__global__ void k_small(const float* __restrict__ vnfc, const float* __restrict__ vw,
                        const float* __restrict__ vb, const float* __restrict__ eab,
                        const float* __restrict__ a1w, const float* __restrict__ a1b,
                        const float* __restrict__ eaw, float* __restrict__ E1) {
    __shared__ float vr[128];
    __shared__ float sM1[512];
    __shared__ float sd1[128];
    int t = threadIdx.x;   // 512
    if (t < 128) {
        float a = vb[t];
#pragma unroll
        for (int k = 0; k < 6; k++) a += vnfc[k] * vw[k * 128 + t];
        vr[t] = a;
    }
    __syncthreads();
    if (t < 128) {
        float a = a1b[t];
        for (int k = 0; k < 128; k++) a += eab[k] * a1w[k * 128 + t];
        for (int k = 0; k < 128; k++) a += vr[k] * a1w[(128 + k) * 128 + t];
        sd1[t] = a;
    }
    {
        int r = t >> 7, j = t & 127;
        float a = 0.f;
        for (int k = 0; k < 128; k++) a += eaw[r * 128 + k] * a1w[k * 128 + j];
        sM1[r * 128 + j] = a;
    }
    __syncthreads();
    if (t < 128) {
        E1[t * 8 + 0] = sM1[t];
        E1[t * 8 + 1] = sM1[128 + t];
        E1[t * 8 + 2] = sM1[256 + t];
        E1[t * 8 + 3] = sM1[384 + t];
        E1[t * 8 + 4] = sd1[t];
        E1[t * 8 + 5] = 0.f; E1[t * 8 + 6] = 0.f; E1[t * 8 + 7] = 0.f;
    }
}

// ---------------- w2bf[j][k] = bf16(a2w[k*64+j])  (B^T table for MFMA) ----------------
__global__ void k_w2bf(const float* __restrict__ a2w, unsigned short* __restrict__ w2bf) {
    int idx = blockIdx.x * 256 + threadIdx.x;   // 8192
    if (idx >= 8192) return;
    int j = idx >> 7, k = idx & 127;
    w2bf[idx] = f2bf(a2w[k * 64 + j]);
}

// ---------------- B matrices: Bs/Bd/Be [L][128][4] ----------------
__global__ void k_bmat(const float* __restrict__ glw, const float* __restrict__ gas,
                       const float* __restrict__ gad, const float* __restrict__ glew,
                       const float* __restrict__ gae, float* __restrict__ Bs,
                       float* __restrict__ Bd, float* __restrict__ Be) {
    int idx = blockIdx.x * 256 + threadIdx.x;
    if (idx >= LL * 128 * 4) return;
    int hh = idx & 3, k = (idx >> 2) & 127, l = idx >> 9;
    const float* lwp = glw  + (size_t)l * 65536 + k * 512 + hh * 128;
    const float* lep = glew + (size_t)l * 65536 + k * 512 + hh * 128;
    const float* sp = gas + l * 512 + hh * 128;
    const float* dp = gad + l * 512 + hh * 128;
    const float* ep = gae + l * 512 + hh * 128;
    float s1 = 0, s2 = 0, s3 = 0;
    for (int c = 0; c < 128; c++) {
        float lv = lwp[c];
        s1 += lv * sp[c];
        s2 += lv * dp[c];
        s3 += lep[c] * ep[c];
    }
    Bs[idx] = s1; Bd[idx] = s2; Be[idx] = s3;
}

// ---------------- PB[4][24], cB[24]: fold ea_proj through Be ----------------
__global__ void k_pb(const float* __restrict__ eaw, const float* __restrict__ eab,
                     const float* __restrict__ Be, float* __restrict__ PB,
                     float* __restrict__ cB) {
    int t = threadIdx.x;
    if (t >= 24) return;
    int l = t >> 2, hh = t & 3;
    const float* bp = Be + l * 512 + hh;
    float s0 = 0, s1 = 0, s2 = 0, s3 = 0, sc = 0;
    for (int k = 0; k < 128; k++) {
        float bv = bp[k * 4];
        s0 += eaw[0 * 128 + k] * bv;
        s1 += eaw[1 * 128 + k] * bv;
        s2 += eaw[2 * 128 + k] * bv;
        s3 += eaw[3 * 128 + k] * bv;
        sc += eab[k] * bv;
    }
    PB[0 * 24 + t] = s0; PB[1 * 24 + t] = s1;
    PB[2 * 24 + t] = s2; PB[3 * 24 + t] = s3;
    cB[t] = sc;
}

// ---- edge gate MLP via MFMA: 64 edges/block, wave w handles m-tile w (16 edges) ----
// a2 = relu(a1) @ w2 : a1 rank-4 in ea -> each lane builds its A-fragment in-register.
__global__ __launch_bounds__(256) void k_edge(
    const float* __restrict__ ea, const float* __restrict__ E1,
    const unsigned short* __restrict__ w2bf, const float* __restrict__ a2b,
    const float* __restrict__ a3w, const float* __restrict__ a3b,
    const float* __restrict__ PB, const float* __restrict__ cB,
    float* __restrict__ aleT, float* __restrict__ gsum) {
    __shared__ float sE1[1024];
    __shared__ float gsh[64];
    int t = threadIdx.x;
    int lane = t & 63;
    int wid = t >> 6;
    for (int z = t; z < 1024; z += 256) sE1[z] = E1[z];
    __syncthreads();
    int base = blockIdx.x * 64;
    int m = lane & 15, q = lane >> 4;
    int e = base + wid * 16 + m;
    float4 ev = *(const float4*)(ea + (size_t)e * 4);
    // acc init with bias (col j = 16*nt + m, same for all 4 rows)
    v4f acc[4];
#pragma unroll
    for (int nt = 0; nt < 4; nt++) {
        float b = a2b[nt * 16 + m];
        acc[nt][0] = b; acc[nt][1] = b; acc[nt][2] = b; acc[nt][3] = b;
    }
#pragma unroll
    for (int ks = 0; ks < 4; ks++) {
        // A fragment: A[m][k], lane owns m=lane&15, k = ks*32 + q*8 + j
        v8s fa;
#pragma unroll
        for (int j = 0; j < 8; j++) {
            int k = ks * 32 + q * 8 + j;
            float4 mm = *(const float4*)(sE1 + k * 8);
            float dk = sE1[k * 8 + 4];
            float xv = fmaxf(dk + ev.x * mm.x + ev.y * mm.y + ev.z * mm.z + ev.w * mm.w, 0.f);
            fa[j] = (short)f2bf(xv);
        }
#pragma unroll
        for (int nt = 0; nt < 4; nt++) {
            // B fragment: B[k][n], lane owns n = nt*16 + m, k = ks*32 + q*8 + j
            v8s fb = *(const v8s*)(w2bf + (size_t)(nt * 16 + m) * 128 + ks * 32 + q * 8);
            acc[nt] = __builtin_amdgcn_mfma_f32_16x16x32_bf16(fa, fb, acc[nt], 0, 0, 0);
        }
    }
    // epilogue: D rows (q*4+r) = edges, col = nt*16 + m. pr[r] = sum_j relu(a2)*a3w[j]
    float pr[4];
#pragma unroll
    for (int r = 0; r < 4; r++) {
        float s = 0.f;
#pragma unroll
        for (int nt = 0; nt < 4; nt++) s += fmaxf(acc[nt][r], 0.f) * a3w[nt * 16 + m];
        pr[r] = s;
    }
#pragma unroll
    for (int d = 1; d <= 8; d <<= 1) {
#pragma unroll
        for (int r = 0; r < 4; r++) pr[r] += __shfl_xor(pr[r], d);
    }
    if (m == 0) {
        float b3 = a3b[0];
#pragma unroll
        for (int r = 0; r < 4; r++)
            gsh[wid * 16 + q * 4 + r] = 1.f / (1.f + __expf(-(pr[r] + b3)));
    }
    __syncthreads();
    if (wid == 0) {
        float g = gsh[lane];
        float4 evv = *(const float4*)(ea + (size_t)(base + lane) * 4);
        float v0 = g, v1 = g * evv.x, v2 = g * evv.y, v3 = g * evv.z, v4 = g * evv.w;
#pragma unroll
        for (int d = 32; d > 0; d >>= 1) {
            v0 += __shfl_down(v0, d); v1 += __shfl_down(v1, d); v2 += __shfl_down(v2, d);
            v3 += __shfl_down(v3, d); v4 += __shfl_down(v4, d);
        }
        if (lane == 0) {
            atomicAdd(&gsum[0], v0); atomicAdd(&gsum[1], v1); atomicAdd(&gsum[2], v2);
            atomicAdd(&gsum[3], v3); atomicAdd(&gsum[4], v4);
        }
    }
    // al_e writes: wave p handles layer-group p (and p+4 for p<2)
#pragma unroll
    for (int rep = 0; rep < 2; rep++) {
        int i4 = (rep == 0) ? wid : (wid < 2 ? wid + 4 : -1);
        if (i4 >= 0) {
            float4 c  = *(const float4*)(cB + i4 * 4);
            float4 p0 = *(const float4*)(PB + 0 * 24 + i4 * 4);
            float4 p1 = *(const float4*)(PB + 1 * 24 + i4 * 4);
            float4 p2 = *(const float4*)(PB + 2 * 24 + i4 * 4);
            float4 p3 = *(const float4*)(PB + 3 * 24 + i4 * 4);
            float g = gsh[lane];
            float4 evv = *(const float4*)(ea + (size_t)(base + lane) * 4);
            float4 o;
            o.x = g * (c.x + evv.x * p0.x + evv.y * p1.x + evv.z * p2.x + evv.w * p3.x);
            o.y = g * (c.y + evv.x * p0.y + evv.y * p1.y + evv.z * p2.y + evv.w * p3.y);
            o.z = g * (c.z + evv.x * p0.z + evv.y * p1.z + evv.z * p2.z + evv.w * p3.z);
            o.w = g * (c.w + evv.x * p0.w + evv.y * p1.w + evv.z * p2.w + evv.w * p3.w);
            *(float4*)(aleT + (size_t)i4 * Ee * 4 + (size_t)(base + lane) * 4) = o;
        }
    }
}

// ---------------- loop-edge al_e from G,S sums ----------------
__global__ void k_lale(const float* __restrict__ gsum, const float* __restrict__ PB,
                       const float* __restrict__ cB, float* __restrict__ lale) {
    int t = threadIdx.x;
    if (t >= 24) return;
    float s = gsum[0] * cB[t] + gsum[1] * PB[t] + gsum[2] * PB[24 + t]
            + gsum[3] * PB[48 + t] + gsum[4] * PB[72 + t];
    lale[t] = s * (1.0f / Ee);
}

// ---------------- counting sort by dst: hist / scan / scatter ----------------
__global__ void k_hist(const int* __restrict__ ei, int* __restrict__ hist) {
    int i = blockIdx.x * 256 + threadIdx.x;
    if (i >= ET) return;
    int d = (i < Ee) ? ei[Ee + i] : (i - Ee);
    atomicAdd(&hist[d], 1);
}

__global__ __launch_bounds__(1024) void k_scan(const int* __restrict__ hist,
                                               int* __restrict__ seg, int* __restrict__ pos) {
    __shared__ int wsums[16];
    __shared__ int carry_s;
    int t = threadIdx.x;
    int lane = t & 63, wid = t >> 6;
    if (t == 0) { carry_s = 0; seg[0] = 0; }
    __syncthreads();
    for (int base = 0; base < Nn; base += 1024) {
        int idx = base + t;
        int v = (idx < Nn) ? hist[idx] : 0;
        int sc = v;
#pragma unroll
        for (int d = 1; d < 64; d <<= 1) {
            int up = __shfl_up(sc, d);
            if (lane >= d) sc += up;
        }
        if (lane == 63) wsums[wid] = sc;
        __syncthreads();
        if (wid == 0) {
            int wv = (lane < 16) ? wsums[lane] : 0;
            int wsc = wv;
#pragma unroll
            for (int d = 1; d < 16; d <<= 1) {
                int up = __shfl_up(wsc, d);
                if (lane >= d) wsc += up;
            }
            if (lane < 16) wsums[lane] = wsc - wv;
        }
        __syncthreads();
        int carry = carry_s;
        int inc = sc + wsums[wid] + carry;
        if (idx < Nn) { seg[idx + 1] = inc; pos[idx] = inc - v; }
        __syncthreads();
        if (t == 1023) carry_s = inc;
        __syncthreads();
    }
}

__global__ void k_scatter(const int* __restrict__ ei, int* __restrict__ pos,
                          int2* __restrict__ pse) {
    int i = blockIdx.x * 256 + threadIdx.x;
    if (i >= ET) return;
    int s, d;
    if (i < Ee) { s = ei[i]; d = ei[Ee + i]; } else { s = d = i - Ee; }
    int idx = atomicAdd(&pos[d], 1);
    pse[idx] = make_int2(s, i);
}

// ---------------- per-layer: xh(bf16) = h @ lw ; als/ald = h @ Bs/Bd ----------------
__global__ __launch_bounds__(512) void k_xh(
    const float* __restrict__ h, const float* __restrict__ lw,
    const float* __restrict__ Bs, const float* __restrict__ Bd,
    unsigned short* __restrict__ xhb, float* __restrict__ als, float* __restrict__ ald) {
    __shared__ float4 hs4[16][32];
    int t = threadIdx.x;   // 512
    int n0 = blockIdx.x * 16;
    {
        int i = t >> 5, kb = t & 31;
        hs4[i][kb] = *(const float4*)(h + (size_t)(n0 + i) * 128 + 4 * kb);
    }
    __syncthreads();
    int g = t >> 7;              // 0..3 -> rows g*4..g*4+3
    int c4 = (t & 127) * 4;
    const float* lwc = lw + c4;
    float4 acc[4];
#pragma unroll
    for (int i = 0; i < 4; i++) acc[i] = make_float4(0.f, 0.f, 0.f, 0.f);
    for (int kb = 0; kb < 32; kb++) {
        float4 w0 = *(const float4*)(lwc + (size_t)(4 * kb + 0) * 512);
        float4 w1 = *(const float4*)(lwc + (size_t)(4 * kb + 1) * 512);
        float4 w2 = *(const float4*)(lwc + (size_t)(4 * kb + 2) * 512);
        float4 w3 = *(const float4*)(lwc + (size_t)(4 * kb + 3) * 512);
#pragma unroll
        for (int i = 0; i < 4; i++) {
            float4 hv = hs4[g * 4 + i][kb];
            acc[i].x += hv.x * w0.x + hv.y * w1.x + hv.z * w2.x + hv.w * w3.x;
            acc[i].y += hv.x * w0.y + hv.y * w1.y + hv.z * w2.y + hv.w * w3.y;
            acc[i].z += hv.x * w0.z + hv.y * w1.z + hv.z * w2.z + hv.w * w3.z;
            acc[i].w += hv.x * w0.w + hv.y * w1.w + hv.z * w2.w + hv.w * w3.w;
        }
    }
#pragma unroll
    for (int i = 0; i < 4; i++) {
        ushort4 st;
        st.x = f2bf(acc[i].x); st.y = f2bf(acc[i].y);
        st.z = f2bf(acc[i].z); st.w = f2bf(acc[i].w);
        *(ushort4*)(xhb + (size_t)(n0 + g * 4 + i) * 512 + c4) = st;
    }
    if (t < 64) {
        int i = t >> 2, hh = t & 3;
        float s1 = 0, s2 = 0;
        for (int kb = 0; kb < 32; kb++) {
            float4 hv = hs4[i][kb];
            s1 += hv.x * Bs[(4 * kb + 0) * 4 + hh] + hv.y * Bs[(4 * kb + 1) * 4 + hh]
                + hv.z * Bs[(4 * kb + 2) * 4 + hh] + hv.w * Bs[(4 * kb + 3) * 4 + hh];
            s2 += hv.x * Bd[(4 * kb + 0) * 4 + hh] + hv.y * Bd[(4 * kb + 1) * 4 + hh]
                + hv.z * Bd[(4 * kb + 2) * 4 + hh] + hv.w * Bd[(4 * kb + 3) * 4 + hh];
        }
        als[(n0 + i) * 4 + hh] = s1;
        ald[(n0 + i) * 4 + hh] = s2;
    }
}

// ---- per-layer fused: logits (gathers) -> LDS -> softmax -> bf16 xh gather -> LN ----
__global__ __launch_bounds__(256) void k_agg(
    const int2* __restrict__ pse, const int* __restrict__ seg,
    const float* __restrict__ als, const float* __restrict__ ald,
    const float* __restrict__ aleT_l, const float* __restrict__ lale_l,
    const unsigned short* __restrict__ xhb, const float* __restrict__ bias,
    const float* __restrict__ lnsc, const float* __restrict__ lnbi,
    float* __restrict__ hio) {
    __shared__ float lgS[4][512];    // [wave][edge*4+head]: logits, then weights
    __shared__ int srcS[4][128];
    int t = threadIdx.x;
    int lane = t & 63;
    int w = t >> 6;
    int n = blockIdx.x * 4 + w;
    int start = seg[n], end = seg[n + 1];
    // ---- phase 1: logits + online (max, sumexp); lane -> head lane&3, edges strided 16 ----
    int h1 = lane & 3;
    float llh1 = lale_l[h1];
    float a1d = ald[n * 4 + h1];
    float m = -INFINITY, ss = 0.f;
    for (int i = start + (lane >> 2); i < end; i += 16) {
        int idx = i - start;
        int2 se = pse[i];
        float alev = se.y < Ee ? aleT_l[(size_t)se.y * 4 + h1] : llh1;
        float av = als[se.x * 4 + h1] + a1d + alev;
        av = av > 0.f ? av : 0.2f * av;
        if (idx < 128) {
            lgS[w][idx * 4 + h1] = av;
            if (h1 == 0) srcS[w][idx] = se.x;
        }
        if (av > m) { ss = ss * __expf(m - av) + 1.f; m = av; }
        else ss += __expf(av - m);
    }
#pragma unroll
    for (int d = 4; d <= 32; d <<= 1) {
        float mo = __shfl_xor(m, d), so = __shfl_xor(ss, d);
        float mm = fmaxf(m, mo);
        float sv = 0.f;
        if (m > -INFINITY) sv += ss * __expf(m - mm);
        if (mo > -INFINITY) sv += so * __expf(mo - mm);
        m = mm; ss = sv;
    }
    float mh0 = __shfl(m, 0), mh1 = __shfl(m, 1), mh2 = __shfl(m, 2), mh3 = __shfl(m, 3);
    float iv0 = 1.f / (__shfl(ss, 0) + 1e-16f), iv1 = 1.f / (__shfl(ss, 1) + 1e-16f);
    float iv2 = 1.f / (__shfl(ss, 2) + 1e-16f), iv3 = 1.f / (__shfl(ss, 3) + 1e-16f);
    int cnt = min(end - start, 128);
    // ---- phase 2a: logits -> weights (in place) ----
    for (int z = lane; z < cnt; z += 64) {
        float4 lg = *(float4*)&lgS[w][z * 4];
        lg.x = __expf(lg.x - mh0) * iv0;
        lg.y = __expf(lg.y - mh1) * iv1;
        lg.z = __expf(lg.z - mh2) * iv2;
        lg.w = __expf(lg.w - mh3) * iv3;
        *(float4*)&lgS[w][z * 4] = lg;
    }
    // ---- phase 2b: serial gather (unroll 2), lane owns 8 channels of 512 ----
    int hp = lane >> 4;
    int c8 = lane * 8;
    float4 acc0 = make_float4(0.f, 0.f, 0.f, 0.f);
    float4 acc1 = make_float4(0.f, 0.f, 0.f, 0.f);
    int i2 = 0;
    for (; i2 + 2 <= cnt; i2 += 2) {
        int s0 = srcS[w][i2], s1 = srcS[w][i2 + 1];
        float wg0 = lgS[w][i2 * 4 + hp], wg1 = lgS[w][i2 * 4 + 4 + hp];
        uint4 u0 = *(const uint4*)(xhb + (size_t)s0 * 512 + c8);
        uint4 u1 = *(const uint4*)(xhb + (size_t)s1 * 512 + c8);
        acc0.x += wg0 * __uint_as_float(u0.x << 16) + wg1 * __uint_as_float(u1.x << 16);
        acc0.y += wg0 * __uint_as_float(u0.x & 0xffff0000u) + wg1 * __uint_as_float(u1.x & 0xffff0000u);
        acc0.z += wg0 * __uint_as_float(u0.y << 16) + wg1 * __uint_as_float(u1.y << 16);
        acc0.w += wg0 * __uint_as_float(u0.y & 0xffff0000u) + wg1 * __uint_as_float(u1.y & 0xffff0000u);
        acc1.x += wg0 * __uint_as_float(u0.z << 16) + wg1 * __uint_as_float(u1.z << 16);
        acc1.y += wg0 * __uint_as_float(u0.z & 0xffff0000u) + wg1 * __uint_as_float(u1.z & 0xffff0000u);
        acc1.z += wg0 * __uint_as_float(u0.w << 16) + wg1 * __uint_as_float(u1.w << 16);
        acc1.w += wg0 * __uint_as_float(u0.w & 0xffff0000u) + wg1 * __uint_as_float(u1.w & 0xffff0000u);
    }
    if (i2 < cnt) {
        int s0 = srcS[w][i2];
        float wg0 = lgS[w][i2 * 4 + hp];
        uint4 u0 = *(const uint4*)(xhb + (size_t)s0 * 512 + c8);
        acc0.x += wg0 * __uint_as_float(u0.x << 16);
        acc0.y += wg0 * __uint_as_float(u0.x & 0xffff0000u);
        acc0.z += wg0 * __uint_as_float(u0.y << 16);
        acc0.w += wg0 * __uint_as_float(u0.y & 0xffff0000u);
        acc1.x += wg0 * __uint_as_float(u0.z << 16);
        acc1.y += wg0 * __uint_as_float(u0.z & 0xffff0000u);
        acc1.z += wg0 * __uint_as_float(u0.w << 16);
        acc1.w += wg0 * __uint_as_float(u0.w & 0xffff0000u);
    }
    // ---- tail (degree > 128: practically never) ----
    for (int i = start + 128; i < end; i++) {
        int2 se = pse[i];
        float mhp = hp == 0 ? mh0 : hp == 1 ? mh1 : hp == 2 ? mh2 : mh3;
        float ivp = hp == 0 ? iv0 : hp == 1 ? iv1 : hp == 2 ? iv2 : iv3;
        float alev = se.y < Ee ? aleT_l[(size_t)se.y * 4 + hp] : lale_l[hp];
        float av = als[se.x * 4 + hp] + ald[n * 4 + hp] + alev;
        av = av > 0.f ? av : 0.2f * av;
        float wg0 = __expf(av - mhp) * ivp;
        uint4 u0 = *(const uint4*)(xhb + (size_t)se.x * 512 + c8);
        acc0.x += wg0 * __uint_as_float(u0.x << 16);
        acc0.y += wg0 * __uint_as_float(u0.x & 0xffff0000u);
        acc0.z += wg0 * __uint_as_float(u0.y << 16);
        acc0.w += wg0 * __uint_as_float(u0.y & 0xffff0000u);
        acc1.x += wg0 * __uint_as_float(u0.z << 16);
        acc1.y += wg0 * __uint_as_float(u0.z & 0xffff0000u);
        acc1.z += wg0 * __uint_as_float(u0.w << 16);
        acc1.w += wg0 * __uint_as_float(u0.w & 0xffff0000u);
    }
    // ---- head mean: xor 16,32 ----
#pragma unroll
    for (int d = 16; d <= 32; d <<= 1) {
        acc0.x += __shfl_xor(acc0.x, d); acc0.y += __shfl_xor(acc0.y, d);
        acc0.z += __shfl_xor(acc0.z, d); acc0.w += __shfl_xor(acc0.w, d);
        acc1.x += __shfl_xor(acc1.x, d); acc1.y += __shfl_xor(acc1.y, d);
        acc1.z += __shfl_xor(acc1.z, d); acc1.w += __shfl_xor(acc1.w, d);
    }
    int cc = (lane & 15) * 8;
    float4 b0 = *(const float4*)(bias + cc), b1 = *(const float4*)(bias + cc + 4);
    float4 h0 = *(const float4*)(hio + (size_t)n * 128 + cc);
    float4 h1v = *(const float4*)(hio + (size_t)n * 128 + cc + 4);
    float4 v0, v1;
    v0.x = h0.x + fmaxf(0.25f * acc0.x + b0.x, 0.f);
    v0.y = h0.y + fmaxf(0.25f * acc0.y + b0.y, 0.f);
    v0.z = h0.z + fmaxf(0.25f * acc0.z + b0.z, 0.f);
    v0.w = h0.w + fmaxf(0.25f * acc0.w + b0.w, 0.f);
    v1.x = h1v.x + fmaxf(0.25f * acc1.x + b1.x, 0.f);
    v1.y = h1v.y + fmaxf(0.25f * acc1.y + b1.y, 0.f);
    v1.z = h1v.z + fmaxf(0.25f * acc1.z + b1.z, 0.f);
    v1.w = h1v.w + fmaxf(0.25f * acc1.w + b1.w, 0.f);
    float s1 = v0.x + v0.y + v0.z + v0.w + v1.x + v1.y + v1.z + v1.w;
    float s2 = v0.x * v0.x + v0.y * v0.y + v0.z * v0.z + v0.w * v0.w
             + v1.x * v1.x + v1.y * v1.y + v1.z * v1.z + v1.w * v1.w;
#pragma unroll
    for (int d = 1; d <= 8; d <<= 1) {
        s1 += __shfl_xor(s1, d); s2 += __shfl_xor(s2, d);
    }
    float mean = s1 * (1.f / 128.f);
    float var = s2 * (1.f / 128.f) - mean * mean;
    float rinv = rsqrtf(var + 1e-5f);
    if (lane < 16) {
        float4 ls0 = *(const float4*)(lnsc + cc), ls1 = *(const float4*)(lnsc + cc + 4);
        float4 lb0 = *(const float4*)(lnbi + cc), lb1 = *(const float4*)(lnbi + cc + 4);
        float4 o0, o1;
        o0.x = (v0.x - mean) * rinv * ls0.x + lb0.x;
        o0.y = (v0.y - mean) * rinv * ls0.y + lb0.y;
        o0.z = (v0.z - mean) * rinv * ls0.z + lb0.z;
        o0.w = (v0.w - mean) * rinv * ls0.w + lb0.w;
        o1.x = (v1.x - mean) * rinv * ls1.x + lb1.x;
        o1.y = (v1.y - mean) * rinv * ls1.y + lb1.y;
        o1.z = (v1.z - mean) * rinv * ls1.z + lb1.z;
        o1.w = (v1.w - mean) * rinv * ls1.w + lb1.w;
        *(float4*)(hio + (size_t)n * 128 + cc) = o0;
        *(float4*)(hio + (size_t)n * 128 + cc + 4) = o1;
    }
}

// ---------------- output projection ----------------
__global__ __launch_bounds__(256) void k_out(
    const float* __restrict__ h, const float* __restrict__ ow,
    const float* __restrict__ ob, float* __restrict__ out) {
    __shared__ float4 hs4[8][32];
    int t = threadIdx.x;
    int n0 = blockIdx.x * 8;
    if (t < 256) {
        int i = t >> 5, kb = t & 31;
        hs4[i][kb] = *(const float4*)(h + (size_t)(n0 + i) * 128 + 4 * kb);
    }
    __syncthreads();
    float acc[8] = {0, 0, 0, 0, 0, 0, 0, 0};
    for (int kb = 0; kb < 32; kb++) {
        float w0 = ow[(4 * kb + 0) * 256 + t];
        float w1 = ow[(4 * kb + 1) * 256 + t];
        float w2 = ow[(4 * kb + 2) * 256 + t];
        float w3 = ow[(4 * kb + 3) * 256 + t];
#pragma unroll
        for (int i = 0; i < 8; i++) {
            float4 hv = hs4[i][kb];
            acc[i] += hv.x * w0 + hv.y * w1 + hv.z * w2 + hv.w * w3;
        }
    }
    float b = ob[t];
#pragma unroll
    for (int i = 0; i < 8; i++) out[(size_t)(n0 + i) * 256 + t] = acc[i] + b;
}

extern "C" void kernel_launch(void* const* d_in, const int* in_sizes, int n_in,
                              void* d_out, int out_size, void* d_ws, size_t ws_size,
                              hipStream_t stream) {
    const float* x    = (const float*)d_in[0];
    const int*   ei   = (const int*)d_in[1];
    const float* ea   = (const float*)d_in[2];
    const float* vnfc = (const float*)d_in[3];
    const float* nw   = (const float*)d_in[4];
    const float* nb   = (const float*)d_in[5];
    const float* eaw  = (const float*)d_in[6];
    const float* eab  = (const float*)d_in[7];
    const float* vw   = (const float*)d_in[8];
    const float* vb   = (const float*)d_in[9];
    const float* a1w  = (const float*)d_in[10];
    const float* a1b  = (const float*)d_in[11];
    const float* a2w  = (const float*)d_in[12];
    const float* a2b  = (const float*)d_in[13];
    const float* a3w  = (const float*)d_in[14];
    const float* a3b  = (const float*)d_in[15];
    const float* glw  = (const float*)d_in[16];
    const float* gas  = (const float*)d_in[17];
    const float* gad  = (const float*)d_in[18];
    const float* glew = (const float*)d_in[19];
    const float* gae  = (const float*)d_in[20];
    const float* gb   = (const float*)d_in[21];
    const float* lnsc = (const float*)d_in[22];
    const float* lnbi = (const float*)d_in[23];
    const float* ow   = (const float*)d_in[24];
    const float* ob   = (const float*)d_in[25];
    float* out = (float*)d_out;

    char* w = (char*)d_ws;
    size_t o = 0;
    auto allocf = [&](size_t cnt) { float* p = (float*)(w + o); o += ((cnt * 4 + 255) / 256) * 256; return p; };
    auto alloci = [&](size_t cnt) { int* p = (int*)(w + o); o += ((cnt * 4 + 255) / 256) * 256; return p; };
    auto allocu = [&](size_t cnt) { unsigned short* p = (unsigned short*)(w + o); o += ((cnt * 2 + 255) / 256) * 256; return p; };
    float* h      = allocf((size_t)Nn * 128);
    unsigned short* xhb = allocu((size_t)Nn * 512);
    unsigned short* w2bf = allocu(8192);
    float* als    = allocf((size_t)Nn * 4);
    float* ald    = allocf((size_t)Nn * 4);
    float* aleT   = allocf((size_t)LL * Ee * 4);
    float* Bs     = allocf(3072);
    float* Bd     = allocf(3072);
    float* Be     = allocf(3072);
    float* E1     = allocf(1024);
    float* PB     = allocf(96);
    float* cB     = allocf(24);
    float* gsum   = allocf(8);
    float* lale   = allocf(32);
    int* seg  = alloci(Nn + 1);
    int* hist = alloci(Nn);
    int* pos  = alloci(Nn);
    int2* pse = (int2*)alloci((size_t)ET * 2);

    hipMemsetAsync(hist, 0, Nn * sizeof(int), stream);
    hipMemsetAsync(gsum, 0, 8 * sizeof(float), stream);

    k_node_embed<<<(Nn * 128 + 255) / 256, 256, 0, stream>>>(x, nw, nb, h);
    k_small<<<1, 512, 0, stream>>>(vnfc, vw, vb, eab, a1w, a1b, eaw, E1);
    k_w2bf<<<32, 256, 0, stream>>>(a2w, w2bf);
    k_bmat<<<(LL * 128 * 4 + 255) / 256, 256, 0, stream>>>(glw, gas, gad, glew, gae, Bs, Bd, Be);
    k_pb<<<1, 32, 0, stream>>>(eaw, eab, Be, PB, cB);
    k_edge<<<Ee / 64, 256, 0, stream>>>(ea, E1, w2bf, a2b, a3w, a3b, PB, cB, aleT, gsum);
    k_hist<<<(ET + 255) / 256, 256, 0, stream>>>(ei, hist);
    k_scan<<<1, 1024, 0, stream>>>(hist, seg, pos);
    k_scatter<<<(ET + 255) / 256, 256, 0, stream>>>(ei, pos, pse);
    k_lale<<<1, 32, 0, stream>>>(gsum, PB, cB, lale);
    for (int l = 0; l < LL; l++) {
        k_xh<<<Nn / 16, 512, 0, stream>>>(h, glw + (size_t)l * 65536, Bs + l * 512, Bd + l * 512,
                                          xhb, als, ald);
        k_agg<<<Nn / 4, 256, 0, stream>>>(pse, seg, als, ald, aleT + (size_t)l * Ee * 4,
                                          lale + l * 4, xhb,
                                          gb + l * 128, lnsc + l * 128, lnbi + l * 128, h);
    }
    k_out<<<Nn / 8, 256, 0, stream>>>(h, ow, ob, out);
}

// Round 8
// 638.844 us; speedup vs baseline: 1.1649x; 1.1649x over previous
//
#include <hip/hip_runtime.h>
#include <hip/hip_bf16.h>
#include <math.h>

#define Nn 10000
#define Ee 160000
#define ET 170000   // Ee + Nn (self loops)
#define LL 6

__device__ __forceinline__ unsigned short f2bf(float v) {
    unsigned int b = __float_as_uint(v);
    b += 0x7fffu + ((b >> 16) & 1u);   // RNE
    return (unsigned short)(b >> 16);
}

// ---------------- node embedding: h = x @ node_w + node_b ----------------
__global__ void k_node_embed(const float* __restrict__ x, const float* __restrict__ nw,
                             const float* __restrict__ nb, float* __restrict__ h) {
    int idx = blockIdx.x * 256 + threadIdx.x;
    if (idx >= Nn * 128) return;
    int n = idx >> 7, c = idx & 127;
    const float* xr = x + (size_t)n * 8;
    float acc = nb[c];
#pragma unroll
    for (int k = 0; k < 8; k++) acc += xr[k] * nw[k * 128 + c];
    h[idx] = acc;
}

// ---------------- small precompute: E1[128][8] = {M1[0..3][k], d1[k], 0,0,0} ----------------
__global__ void k_small(const float* __restrict__ vnfc, const float* __restrict__ vw,
                        const float* __restrict__ vb, const float* __restrict__ eab,
                        const float* __restrict__ a1w, const float* __restrict__ a1b,
                        const float* __restrict__ eaw, float* __restrict__ E1) {
    __shared__ float vr[128];
    __shared__ float sM1[512];
    __shared__ float sd1[128];
    int t = threadIdx.x;   // 512
    if (t < 128) {
        float a = vb[t];
#pragma unroll
        for (int k = 0; k < 6; k++) a += vnfc[k] * vw[k * 128 + t];
        vr[t] = a;
    }
    __syncthreads();
    if (t < 128) {
        float a = a1b[t];
        for (int k = 0; k < 128; k++) a += eab[k] * a1w[k * 128 + t];
        for (int k = 0; k < 128; k++) a += vr[k] * a1w[(128 + k) * 128 + t];
        sd1[t] = a;
    }
    {
        int r = t >> 7, j = t & 127;
        float a = 0.f;
        for (int k = 0; k < 128; k++) a += eaw[r * 128 + k] * a1w[k * 128 + j];
        sM1[r * 128 + j] = a;
    }
    __syncthreads();
    if (t < 128) {
        E1[t * 8 + 0] = sM1[t];
        E1[t * 8 + 1] = sM1[128 + t];
        E1[t * 8 + 2] = sM1[256 + t];
        E1[t * 8 + 3] = sM1[384 + t];
        E1[t * 8 + 4] = sd1[t];
        E1[t * 8 + 5] = 0.f; E1[t * 8 + 6] = 0.f; E1[t * 8 + 7] = 0.f;
    }
}

// ---------------- B matrices: Bs/Bd/Be [L][128][4] ----------------
__global__ void k_bmat(const float* __restrict__ glw, const float* __restrict__ gas,
                       const float* __restrict__ gad, const float* __restrict__ glew,
                       const float* __restrict__ gae, float* __restrict__ Bs,
                       float* __restrict__ Bd, float* __restrict__ Be) {
    int idx = blockIdx.x * 256 + threadIdx.x;
    if (idx >= LL * 128 * 4) return;
    int hh = idx & 3, k = (idx >> 2) & 127, l = idx >> 9;
    const float* lwp = glw  + (size_t)l * 65536 + k * 512 + hh * 128;
    const float* lep = glew + (size_t)l * 65536 + k * 512 + hh * 128;
    const float* sp = gas + l * 512 + hh * 128;
    const float* dp = gad + l * 512 + hh * 128;
    const float* ep = gae + l * 512 + hh * 128;
    float s1 = 0, s2 = 0, s3 = 0;
    for (int c = 0; c < 128; c++) {
        float lv = lwp[c];
        s1 += lv * sp[c];
        s2 += lv * dp[c];
        s3 += lep[c] * ep[c];
    }
    Bs[idx] = s1; Bd[idx] = s2; Be[idx] = s3;
}

// ---------------- PB[4][24], cB[24]: fold ea_proj through Be ----------------
__global__ void k_pb(const float* __restrict__ eaw, const float* __restrict__ eab,
                     const float* __restrict__ Be, float* __restrict__ PB,
                     float* __restrict__ cB) {
    int t = threadIdx.x;
    if (t >= 24) return;
    int l = t >> 2, hh = t & 3;
    const float* bp = Be + l * 512 + hh;
    float s0 = 0, s1 = 0, s2 = 0, s3 = 0, sc = 0;
    for (int k = 0; k < 128; k++) {
        float bv = bp[k * 4];
        s0 += eaw[0 * 128 + k] * bv;
        s1 += eaw[1 * 128 + k] * bv;
        s2 += eaw[2 * 128 + k] * bv;
        s3 += eaw[3 * 128 + k] * bv;
        sc += eab[k] * bv;
    }
    PB[0 * 24 + t] = s0; PB[1 * 24 + t] = s1;
    PB[2 * 24 + t] = s2; PB[3 * 24 + t] = s3;
    cB[t] = sc;
}

// ---- edge gate MLP: LDS weights; 256 edges/block, 4/lane, 4 waves split the 64 j ----
__global__ __launch_bounds__(256) void k_edge(
    const float* __restrict__ ea, const float* __restrict__ E1,
    const float* __restrict__ a2w, const float* __restrict__ a2b,
    const float* __restrict__ a3w, const float* __restrict__ a3b,
    const float* __restrict__ PB, const float* __restrict__ cB,
    float* __restrict__ aleT, float* __restrict__ gsum) {
    __shared__ float sw2[128 * 64];   // 32 KB, [k][j]
    __shared__ float4 sM[128];
    __shared__ float sD[128];
    __shared__ float prs[4][256];
    __shared__ float gsh[256];
    int t = threadIdx.x;
    int lane = t & 63;
    int p = t >> 6;
    int ps = __builtin_amdgcn_readfirstlane(p);
    for (int z = t; z < 2048; z += 256) ((float4*)sw2)[z] = ((const float4*)a2w)[z];
    if (t < 128) { sM[t] = *(const float4*)(E1 + t * 8); sD[t] = E1[t * 8 + 4]; }
    __syncthreads();
    int eb = blockIdx.x * 256 + lane;
    float4 ev[4];
#pragma unroll
    for (int r = 0; r < 4; r++) ev[r] = *(const float4*)(ea + (size_t)(eb + r * 64) * 4);
    float acc[4][16];
#pragma unroll
    for (int j = 0; j < 16; j++) {
        float b = a2b[ps * 16 + j];
#pragma unroll
        for (int r = 0; r < 4; r++) acc[r][j] = b;
    }
    const float* w2base = sw2 + ps * 16;
    for (int k = 0; k < 128; k++) {
        float4 m = sM[k];
        float dk = sD[k];
        float xx[4];
#pragma unroll
        for (int r = 0; r < 4; r++)
            xx[r] = fmaxf(dk + ev[r].x * m.x + ev[r].y * m.y + ev[r].z * m.z + ev[r].w * m.w, 0.f);
        const float* w2r = w2base + k * 64;
#pragma unroll
        for (int j4 = 0; j4 < 4; j4++) {
            float4 wv = *(const float4*)(w2r + j4 * 4);
#pragma unroll
            for (int r = 0; r < 4; r++) {
                acc[r][4 * j4 + 0] += xx[r] * wv.x;
                acc[r][4 * j4 + 1] += xx[r] * wv.y;
                acc[r][4 * j4 + 2] += xx[r] * wv.z;
                acc[r][4 * j4 + 3] += xx[r] * wv.w;
            }
        }
    }
#pragma unroll
    for (int r = 0; r < 4; r++) {
        float pr = 0.f;
#pragma unroll
        for (int j = 0; j < 16; j++) pr += fmaxf(acc[r][j], 0.f) * a3w[ps * 16 + j];
        prs[p][r * 64 + lane] = pr;
    }
    __syncthreads();
    if (p == 0) {
        float v0 = 0.f, v1 = 0.f, v2 = 0.f, v3 = 0.f, v4 = 0.f;
#pragma unroll
        for (int rep = 0; rep < 4; rep++) {
            int le = rep * 64 + lane;
            float tot = prs[0][le] + prs[1][le] + prs[2][le] + prs[3][le] + a3b[0];
            float g = 1.f / (1.f + __expf(-tot));
            gsh[le] = g;
            float4 evv = ev[rep];
            v0 += g; v1 += g * evv.x; v2 += g * evv.y; v3 += g * evv.z; v4 += g * evv.w;
        }
#pragma unroll
        for (int d = 32; d > 0; d >>= 1) {
            v0 += __shfl_down(v0, d); v1 += __shfl_down(v1, d); v2 += __shfl_down(v2, d);
            v3 += __shfl_down(v3, d); v4 += __shfl_down(v4, d);
        }
        if (lane == 0) {
            atomicAdd(&gsum[0], v0); atomicAdd(&gsum[1], v1); atomicAdd(&gsum[2], v2);
            atomicAdd(&gsum[3], v3); atomicAdd(&gsum[4], v4);
        }
    }
    __syncthreads();
#pragma unroll
    for (int rep = 0; rep < 2; rep++) {
        int i4 = (rep == 0) ? ps : (ps < 2 ? ps + 4 : -1);
        if (i4 >= 0) {
            float4 c  = *(const float4*)(cB + i4 * 4);
            float4 p0 = *(const float4*)(PB + 0 * 24 + i4 * 4);
            float4 p1 = *(const float4*)(PB + 1 * 24 + i4 * 4);
            float4 p2 = *(const float4*)(PB + 2 * 24 + i4 * 4);
            float4 p3 = *(const float4*)(PB + 3 * 24 + i4 * 4);
#pragma unroll
            for (int r = 0; r < 4; r++) {
                float g = gsh[r * 64 + lane];
                float4 evv = ev[r];
                float4 o;
                o.x = g * (c.x + evv.x * p0.x + evv.y * p1.x + evv.z * p2.x + evv.w * p3.x);
                o.y = g * (c.y + evv.x * p0.y + evv.y * p1.y + evv.z * p2.y + evv.w * p3.y);
                o.z = g * (c.z + evv.x * p0.z + evv.y * p1.z + evv.z * p2.z + evv.w * p3.z);
                o.w = g * (c.w + evv.x * p0.w + evv.y * p1.w + evv.z * p2.w + evv.w * p3.w);
                *(float4*)(aleT + (size_t)i4 * Ee * 4 + (size_t)(eb + r * 64) * 4) = o;
            }
        }
    }
}

// ---------------- loop-edge al_e from G,S sums ----------------
__global__ void k_lale(const float* __restrict__ gsum, const float* __restrict__ PB,
                       const float* __restrict__ cB, float* __restrict__ lale) {
    int t = threadIdx.x;
    if (t >= 24) return;
    float s = gsum[0] * cB[t] + gsum[1] * PB[t] + gsum[2] * PB[24 + t]
            + gsum[3] * PB[48 + t] + gsum[4] * PB[72 + t];
    lale[t] = s * (1.0f / Ee);
}

// ---------------- counting sort by dst: hist / scan / scatter ----------------
__global__ void k_hist(const int* __restrict__ ei, int* __restrict__ hist) {
    int i = blockIdx.x * 256 + threadIdx.x;
    if (i >= ET) return;
    int d = (i < Ee) ? ei[Ee + i] : (i - Ee);
    atomicAdd(&hist[d], 1);
}

__global__ __launch_bounds__(1024) void k_scan(const int* __restrict__ hist,
                                               int* __restrict__ seg, int* __restrict__ pos) {
    __shared__ int wsums[16];
    __shared__ int carry_s;
    int t = threadIdx.x;
    int lane = t & 63, wid = t >> 6;
    if (t == 0) { carry_s = 0; seg[0] = 0; }
    __syncthreads();
    for (int base = 0; base < Nn; base += 1024) {
        int idx = base + t;
        int v = (idx < Nn) ? hist[idx] : 0;
        int sc = v;
#pragma unroll
        for (int d = 1; d < 64; d <<= 1) {
            int up = __shfl_up(sc, d);
            if (lane >= d) sc += up;
        }
        if (lane == 63) wsums[wid] = sc;
        __syncthreads();
        if (wid == 0) {
            int wv = (lane < 16) ? wsums[lane] : 0;
            int wsc = wv;
#pragma unroll
            for (int d = 1; d < 16; d <<= 1) {
                int up = __shfl_up(wsc, d);
                if (lane >= d) wsc += up;
            }
            if (lane < 16) wsums[lane] = wsc - wv;
        }
        __syncthreads();
        int carry = carry_s;
        int inc = sc + wsums[wid] + carry;
        if (idx < Nn) { seg[idx + 1] = inc; pos[idx] = inc - v; }
        __syncthreads();
        if (t == 1023) carry_s = inc;
        __syncthreads();
    }
}

__global__ void k_scatter(const int* __restrict__ ei, int* __restrict__ pos,
                          int2* __restrict__ pse) {
    int i = blockIdx.x * 256 + threadIdx.x;
    if (i >= ET) return;
    int s, d;
    if (i < Ee) { s = ei[i]; d = ei[Ee + i]; } else { s = d = i - Ee; }
    int idx = atomicAdd(&pos[d], 1);
    pse[idx] = make_int2(s, i);
}

// ---------------- per-layer: xh(bf16) = h @ lw ; als/ald = h @ Bs/Bd ----------------
__global__ __launch_bounds__(512) void k_xh(
    const float* __restrict__ h, const float* __restrict__ lw,
    const float* __restrict__ Bs, const float* __restrict__ Bd,
    unsigned short* __restrict__ xhb, float* __restrict__ als, float* __restrict__ ald) {
    __shared__ float4 hs4[16][32];
    int t = threadIdx.x;   // 512
    int n0 = blockIdx.x * 16;
    {
        int i = t >> 5, kb = t & 31;
        hs4[i][kb] = *(const float4*)(h + (size_t)(n0 + i) * 128 + 4 * kb);
    }
    __syncthreads();
    int g = t >> 7;              // 0..3 -> rows g*4..g*4+3
    int c4 = (t & 127) * 4;
    const float* lwc = lw + c4;
    float4 acc[4];
#pragma unroll
    for (int i = 0; i < 4; i++) acc[i] = make_float4(0.f, 0.f, 0.f, 0.f);
    for (int kb = 0; kb < 32; kb++) {
        float4 w0 = *(const float4*)(lwc + (size_t)(4 * kb + 0) * 512);
        float4 w1 = *(const float4*)(lwc + (size_t)(4 * kb + 1) * 512);
        float4 w2 = *(const float4*)(lwc + (size_t)(4 * kb + 2) * 512);
        float4 w3 = *(const float4*)(lwc + (size_t)(4 * kb + 3) * 512);
#pragma unroll
        for (int i = 0; i < 4; i++) {
            float4 hv = hs4[g * 4 + i][kb];
            acc[i].x += hv.x * w0.x + hv.y * w1.x + hv.z * w2.x + hv.w * w3.x;
            acc[i].y += hv.x * w0.y + hv.y * w1.y + hv.z * w2.y + hv.w * w3.y;
            acc[i].z += hv.x * w0.z + hv.y * w1.z + hv.z * w2.z + hv.w * w3.z;
            acc[i].w += hv.x * w0.w + hv.y * w1.w + hv.z * w2.w + hv.w * w3.w;
        }
    }
#pragma unroll
    for (int i = 0; i < 4; i++) {
        ushort4 st;
        st.x = f2bf(acc[i].x); st.y = f2bf(acc[i].y);
        st.z = f2bf(acc[i].z); st.w = f2bf(acc[i].w);
        *(ushort4*)(xhb + (size_t)(n0 + g * 4 + i) * 512 + c4) = st;
    }
    if (t < 64) {
        int i = t >> 2, hh = t & 3;
        float s1 = 0, s2 = 0;
        for (int kb = 0; kb < 32; kb++) {
            float4 hv = hs4[i][kb];
            s1 += hv.x * Bs[(4 * kb + 0) * 4 + hh] + hv.y * Bs[(4 * kb + 1) * 4 + hh]
                + hv.z * Bs[(4 * kb + 2) * 4 + hh] + hv.w * Bs[(4 * kb + 3) * 4 + hh];
            s2 += hv.x * Bd[(4 * kb + 0) * 4 + hh] + hv.y * Bd[(4 * kb + 1) * 4 + hh]
                + hv.z * Bd[(4 * kb + 2) * 4 + hh] + hv.w * Bd[(4 * kb + 3) * 4 + hh];
        }
        als[(n0 + i) * 4 + hh] = s1;
        ald[(n0 + i) * 4 + hh] = s2;
    }
}

// ---- per-layer fused agg: 2 waves per node (halved serial chains), 2 nodes/block ----
__global__ __launch_bounds__(256) void k_agg(
    const int2* __restrict__ pse, const int* __restrict__ seg,
    const float* __restrict__ als, const float* __restrict__ ald,
    const float* __restrict__ aleT_l, const float* __restrict__ lale_l,
    const unsigned short* __restrict__ xhb, const float* __restrict__ bias,
    const float* __restrict__ lnsc, const float* __restrict__ lnbi,
    float* __restrict__ hio) {
    __shared__ float lgS[2][512];      // [node][edge*4+head] logits -> weights
    __shared__ int srcS[2][128];
    __shared__ float msS[2][2][8];     // [node][wave][{m0..3, ss0..3}]
    __shared__ float part[2][128];     // wave-1 partial channel sums
    int t = threadIdx.x;
    int lane = t & 63;
    int wv = (t >> 6) & 1;   // sub-wave within node
    int w = t >> 7;          // node slot 0/1
    int n = blockIdx.x * 2 + w;
    int start = seg[n], end = seg[n + 1];
    int deg = end - start;
    int half = (deg + 1) >> 1;
    int s0 = start + wv * half;
    int e0 = wv ? end : start + half;
    // ---- phase 1: logits + online (max,sumexp) over this wave's half ----
    int h1 = lane & 3;
    float llh1 = lale_l[h1];
    float a1d = ald[n * 4 + h1];
    float m = -INFINITY, ss = 0.f;
    for (int i = s0 + (lane >> 2); i < e0; i += 16) {
        int idx = i - start;
        int2 se = pse[i];
        float alev = se.y < Ee ? aleT_l[(size_t)se.y * 4 + h1] : llh1;
        float av = als[se.x * 4 + h1] + a1d + alev;
        av = av > 0.f ? av : 0.2f * av;
        if (idx < 128) {
            lgS[w][idx * 4 + h1] = av;
            if (h1 == 0) srcS[w][idx] = se.x;
        }
        if (av > m) { ss = ss * __expf(m - av) + 1.f; m = av; }
        else ss += __expf(av - m);
    }
#pragma unroll
    for (int d = 4; d <= 32; d <<= 1) {
        float mo = __shfl_xor(m, d), so = __shfl_xor(ss, d);
        float mm = fmaxf(m, mo);
        float sv = 0.f;
        if (m > -INFINITY) sv += ss * __expf(m - mm);
        if (mo > -INFINITY) sv += so * __expf(mo - mm);
        m = mm; ss = sv;
    }
    if (lane < 4) { msS[w][wv][lane] = m; msS[w][wv][4 + lane] = ss; }
    __syncthreads();
    {   // merge with the other wave's stats
        float mo = msS[w][1 - wv][h1], so = msS[w][1 - wv][4 + h1];
        float mm = fmaxf(m, mo);
        float sv = 0.f;
        if (m > -INFINITY) sv += ss * __expf(m - mm);
        if (mo > -INFINITY) sv += so * __expf(mo - mm);
        m = mm; ss = sv;
    }
    float mh0 = __shfl(m, 0), mh1 = __shfl(m, 1), mh2 = __shfl(m, 2), mh3 = __shfl(m, 3);
    float iv0 = 1.f / (__shfl(ss, 0) + 1e-16f), iv1 = 1.f / (__shfl(ss, 1) + 1e-16f);
    float iv2 = 1.f / (__shfl(ss, 2) + 1e-16f), iv3 = 1.f / (__shfl(ss, 3) + 1e-16f);
    // ---- phase 2a: this wave's logits -> weights ----
    int lo = wv * half;
    int hi = min(wv ? deg : half, 128);
    for (int z = lo + lane; z < hi; z += 64) {
        float4 lg = *(float4*)&lgS[w][z * 4];
        lg.x = __expf(lg.x - mh0) * iv0;
        lg.y = __expf(lg.y - mh1) * iv1;
        lg.z = __expf(lg.z - mh2) * iv2;
        lg.w = __expf(lg.w - mh3) * iv3;
        *(float4*)&lgS[w][z * 4] = lg;
    }
    // ---- phase 2b: serial gather over this wave's half (unroll 2) ----
    int hp = lane >> 4;
    int c8 = lane * 8;
    float4 acc0 = make_float4(0.f, 0.f, 0.f, 0.f);
    float4 acc1 = make_float4(0.f, 0.f, 0.f, 0.f);
    int i2 = lo;
    for (; i2 + 2 <= hi; i2 += 2) {
        int sa = srcS[w][i2], sb = srcS[w][i2 + 1];
        float wg0 = lgS[w][i2 * 4 + hp], wg1 = lgS[w][i2 * 4 + 4 + hp];
        uint4 u0 = *(const uint4*)(xhb + (size_t)sa * 512 + c8);
        uint4 u1 = *(const uint4*)(xhb + (size_t)sb * 512 + c8);
        acc0.x += wg0 * __uint_as_float(u0.x << 16) + wg1 * __uint_as_float(u1.x << 16);
        acc0.y += wg0 * __uint_as_float(u0.x & 0xffff0000u) + wg1 * __uint_as_float(u1.x & 0xffff0000u);
        acc0.z += wg0 * __uint_as_float(u0.y << 16) + wg1 * __uint_as_float(u1.y << 16);
        acc0.w += wg0 * __uint_as_float(u0.y & 0xffff0000u) + wg1 * __uint_as_float(u1.y & 0xffff0000u);
        acc1.x += wg0 * __uint_as_float(u0.z << 16) + wg1 * __uint_as_float(u1.z << 16);
        acc1.y += wg0 * __uint_as_float(u0.z & 0xffff0000u) + wg1 * __uint_as_float(u1.z & 0xffff0000u);
        acc1.z += wg0 * __uint_as_float(u0.w << 16) + wg1 * __uint_as_float(u1.w << 16);
        acc1.w += wg0 * __uint_as_float(u0.w & 0xffff0000u) + wg1 * __uint_as_float(u1.w & 0xffff0000u);
    }
    if (i2 < hi) {
        int sa = srcS[w][i2];
        float wg0 = lgS[w][i2 * 4 + hp];
        uint4 u0 = *(const uint4*)(xhb + (size_t)sa * 512 + c8);
        acc0.x += wg0 * __uint_as_float(u0.x << 16);
        acc0.y += wg0 * __uint_as_float(u0.x & 0xffff0000u);
        acc0.z += wg0 * __uint_as_float(u0.y << 16);
        acc0.w += wg0 * __uint_as_float(u0.y & 0xffff0000u);
        acc1.x += wg0 * __uint_as_float(u0.z << 16);
        acc1.y += wg0 * __uint_as_float(u0.z & 0xffff0000u);
        acc1.z += wg0 * __uint_as_float(u0.w << 16);
        acc1.w += wg0 * __uint_as_float(u0.w & 0xffff0000u);
    }
    // ---- tail (node degree > 128: recompute from global) ----
    float mhp = hp == 0 ? mh0 : hp == 1 ? mh1 : hp == 2 ? mh2 : mh3;
    float ivp = hp == 0 ? iv0 : hp == 1 ? iv1 : hp == 2 ? iv2 : iv3;
    for (int i = start + max(lo, 128); i < e0; i++) {
        int2 se = pse[i];
        float alev = se.y < Ee ? aleT_l[(size_t)se.y * 4 + hp] : lale_l[hp];
        float av = als[se.x * 4 + hp] + ald[n * 4 + hp] + alev;
        av = av > 0.f ? av : 0.2f * av;
        float wg0 = __expf(av - mhp) * ivp;
        uint4 u0 = *(const uint4*)(xhb + (size_t)se.x * 512 + c8);
        acc0.x += wg0 * __uint_as_float(u0.x << 16);
        acc0.y += wg0 * __uint_as_float(u0.x & 0xffff0000u);
        acc0.z += wg0 * __uint_as_float(u0.y << 16);
        acc0.w += wg0 * __uint_as_float(u0.y & 0xffff0000u);
        acc1.x += wg0 * __uint_as_float(u0.z << 16);
        acc1.y += wg0 * __uint_as_float(u0.z & 0xffff0000u);
        acc1.z += wg0 * __uint_as_float(u0.w << 16);
        acc1.w += wg0 * __uint_as_float(u0.w & 0xffff0000u);
    }
    // ---- head mean within wave: xor 16,32 ----
#pragma unroll
    for (int d = 16; d <= 32; d <<= 1) {
        acc0.x += __shfl_xor(acc0.x, d); acc0.y += __shfl_xor(acc0.y, d);
        acc0.z += __shfl_xor(acc0.z, d); acc0.w += __shfl_xor(acc0.w, d);
        acc1.x += __shfl_xor(acc1.x, d); acc1.y += __shfl_xor(acc1.y, d);
        acc1.z += __shfl_xor(acc1.z, d); acc1.w += __shfl_xor(acc1.w, d);
    }
    int cc = (lane & 15) * 8;
    if (wv == 1 && lane < 16) {
        *(float4*)&part[w][cc] = acc0;
        *(float4*)&part[w][cc + 4] = acc1;
    }
    __syncthreads();
    if (wv == 0) {
        float4 p0 = *(const float4*)&part[w][cc];
        float4 p1 = *(const float4*)&part[w][cc + 4];
        acc0.x += p0.x; acc0.y += p0.y; acc0.z += p0.z; acc0.w += p0.w;
        acc1.x += p1.x; acc1.y += p1.y; acc1.z += p1.z; acc1.w += p1.w;
        float4 b0 = *(const float4*)(bias + cc), b1 = *(const float4*)(bias + cc + 4);
        float4 h0 = *(const float4*)(hio + (size_t)n * 128 + cc);
        float4 h1v = *(const float4*)(hio + (size_t)n * 128 + cc + 4);
        float4 v0, v1;
        v0.x = h0.x + fmaxf(0.25f * acc0.x + b0.x, 0.f);
        v0.y = h0.y + fmaxf(0.25f * acc0.y + b0.y, 0.f);
        v0.z = h0.z + fmaxf(0.25f * acc0.z + b0.z, 0.f);
        v0.w = h0.w + fmaxf(0.25f * acc0.w + b0.w, 0.f);
        v1.x = h1v.x + fmaxf(0.25f * acc1.x + b1.x, 0.f);
        v1.y = h1v.y + fmaxf(0.25f * acc1.y + b1.y, 0.f);
        v1.z = h1v.z + fmaxf(0.25f * acc1.z + b1.z, 0.f);
        v1.w = h1v.w + fmaxf(0.25f * acc1.w + b1.w, 0.f);
        float s1 = v0.x + v0.y + v0.z + v0.w + v1.x + v1.y + v1.z + v1.w;
        float s2 = v0.x * v0.x + v0.y * v0.y + v0.z * v0.z + v0.w * v0.w
                 + v1.x * v1.x + v1.y * v1.y + v1.z * v1.z + v1.w * v1.w;
#pragma unroll
        for (int d = 1; d <= 8; d <<= 1) {
            s1 += __shfl_xor(s1, d); s2 += __shfl_xor(s2, d);
        }
        float mean = s1 * (1.f / 128.f);
        float var = s2 * (1.f / 128.f) - mean * mean;
        float rinv = rsqrtf(var + 1e-5f);
        if (lane < 16) {
            float4 ls0 = *(const float4*)(lnsc + cc), ls1 = *(const float4*)(lnsc + cc + 4);
            float4 lb0 = *(const float4*)(lnbi + cc), lb1 = *(const float4*)(lnbi + cc + 4);
            float4 o0, o1;
            o0.x = (v0.x - mean) * rinv * ls0.x + lb0.x;
            o0.y = (v0.y - mean) * rinv * ls0.y + lb0.y;
            o0.z = (v0.z - mean) * rinv * ls0.z + lb0.z;
            o0.w = (v0.w - mean) * rinv * ls0.w + lb0.w;
            o1.x = (v1.x - mean) * rinv * ls1.x + lb1.x;
            o1.y = (v1.y - mean) * rinv * ls1.y + lb1.y;
            o1.z = (v1.z - mean) * rinv * ls1.z + lb1.z;
            o1.w = (v1.w - mean) * rinv * ls1.w + lb1.w;
            *(float4*)(hio + (size_t)n * 128 + cc) = o0;
            *(float4*)(hio + (size_t)n * 128 + cc + 4) = o1;
        }
    }
}

// ---------------- output projection ----------------
__global__ __launch_bounds__(256) void k_out(
    const float* __restrict__ h, const float* __restrict__ ow,
    const float* __restrict__ ob, float* __restrict__ out) {
    __shared__ float4 hs4[8][32];
    int t = threadIdx.x;
    int n0 = blockIdx.x * 8;
    if (t < 256) {
        int i = t >> 5, kb = t & 31;
        hs4[i][kb] = *(const float4*)(h + (size_t)(n0 + i) * 128 + 4 * kb);
    }
    __syncthreads();
    float acc[8] = {0, 0, 0, 0, 0, 0, 0, 0};
    for (int kb = 0; kb < 32; kb++) {
        float w0 = ow[(4 * kb + 0) * 256 + t];
        float w1 = ow[(4 * kb + 1) * 256 + t];
        float w2 = ow[(4 * kb + 2) * 256 + t];
        float w3 = ow[(4 * kb + 3) * 256 + t];
#pragma unroll
        for (int i = 0; i < 8; i++) {
            float4 hv = hs4[i][kb];
            acc[i] += hv.x * w0 + hv.y * w1 + hv.z * w2 + hv.w * w3;
        }
    }
    float b = ob[t];
#pragma unroll
    for (int i = 0; i < 8; i++) out[(size_t)(n0 + i) * 256 + t] = acc[i] + b;
}

extern "C" void kernel_launch(void* const* d_in, const int* in_sizes, int n_in,
                              void* d_out, int out_size, void* d_ws, size_t ws_size,
                              hipStream_t stream) {
    const float* x    = (const float*)d_in[0];
    const int*   ei   = (const int*)d_in[1];
    const float* ea   = (const float*)d_in[2];
    const float* vnfc = (const float*)d_in[3];
    const float* nw   = (const float*)d_in[4];
    const float* nb   = (const float*)d_in[5];
    const float* eaw  = (const float*)d_in[6];
    const float* eab  = (const float*)d_in[7];
    const float* vw   = (const float*)d_in[8];
    const float* vb   = (const float*)d_in[9];
    const float* a1w  = (const float*)d_in[10];
    const float* a1b  = (const float*)d_in[11];
    const float* a2w  = (const float*)d_in[12];
    const float* a2b  = (const float*)d_in[13];
    const float* a3w  = (const float*)d_in[14];
    const float* a3b  = (const float*)d_in[15];
    const float* glw  = (const float*)d_in[16];
    const float* gas  = (const float*)d_in[17];
    const float* gad  = (const float*)d_in[18];
    const float* glew = (const float*)d_in[19];
    const float* gae  = (const float*)d_in[20];
    const float* gb   = (const float*)d_in[21];
    const float* lnsc = (const float*)d_in[22];
    const float* lnbi = (const float*)d_in[23];
    const float* ow   = (const float*)d_in[24];
    const float* ob   = (const float*)d_in[25];
    float* out = (float*)d_out;

    char* w = (char*)d_ws;
    size_t o = 0;
    auto allocf = [&](size_t cnt) { float* p = (float*)(w + o); o += ((cnt * 4 + 255) / 256) * 256; return p; };
    auto alloci = [&](size_t cnt) { int* p = (int*)(w + o); o += ((cnt * 4 + 255) / 256) * 256; return p; };
    auto allocu = [&](size_t cnt) { unsigned short* p = (unsigned short*)(w + o); o += ((cnt * 2 + 255) / 256) * 256; return p; };
    float* h      = allocf((size_t)Nn * 128);
    unsigned short* xhb = allocu((size_t)Nn * 512);
    float* als    = allocf((size_t)Nn * 4);
    float* ald    = allocf((size_t)Nn * 4);
    float* aleT   = allocf((size_t)LL * Ee * 4);
    float* Bs     = allocf(3072);
    float* Bd     = allocf(3072);
    float* Be     = allocf(3072);
    float* E1     = allocf(1024);
    float* PB     = allocf(96);
    float* cB     = allocf(24);
    float* gsum   = allocf(8);
    float* lale   = allocf(32);
    int* seg  = alloci(Nn + 1);
    int* hist = alloci(Nn);
    int* pos  = alloci(Nn);
    int2* pse = (int2*)alloci((size_t)ET * 2);

    hipMemsetAsync(hist, 0, Nn * sizeof(int), stream);
    hipMemsetAsync(gsum, 0, 8 * sizeof(float), stream);

    k_node_embed<<<(Nn * 128 + 255) / 256, 256, 0, stream>>>(x, nw, nb, h);
    k_small<<<1, 512, 0, stream>>>(vnfc, vw, vb, eab, a1w, a1b, eaw, E1);
    k_bmat<<<(LL * 128 * 4 + 255) / 256, 256, 0, stream>>>(glw, gas, gad, glew, gae, Bs, Bd, Be);
    k_pb<<<1, 32, 0, stream>>>(eaw, eab, Be, PB, cB);
    k_edge<<<Ee / 256, 256, 0, stream>>>(ea, E1, a2w, a2b, a3w, a3b, PB, cB, aleT, gsum);
    k_hist<<<(ET + 255) / 256, 256, 0, stream>>>(ei, hist);
    k_scan<<<1, 1024, 0, stream>>>(hist, seg, pos);
    k_scatter<<<(ET + 255) / 256, 256, 0, stream>>>(ei, pos, pse);
    k_lale<<<1, 32, 0, stream>>>(gsum, PB, cB, lale);
    for (int l = 0; l < LL; l++) {
        k_xh<<<Nn / 16, 512, 0, stream>>>(h, glw + (size_t)l * 65536, Bs + l * 512, Bd + l * 512,
                                          xhb, als, ald);
        k_agg<<<Nn / 2, 256, 0, stream>>>(pse, seg, als, ald, aleT + (size_t)l * Ee * 4,
                                          lale + l * 4, xhb,
                                          gb + l * 128, lnsc + l * 128, lnbi + l * 128, h);
    }
    k_out<<<Nn / 8, 256, 0, stream>>>(h, ow, ob, out);
}

// Round 9
// 569.645 us; speedup vs baseline: 1.3064x; 1.1215x over previous
//
#include <hip/hip_runtime.h>
#include <hip/hip_bf16.h>
#include <math.h>

#define Nn 10000
#define Ee 160000
#define ET 170000   // Ee + Nn (self loops)
#define LL 6

typedef short v8s __attribute__((ext_vector_type(8)));
typedef float v4f __attribute__((ext_vector_type(4)));
typedef float v2f __attribute__((ext_vector_type(2)));

__device__ __forceinline__ unsigned short f2bf(float v) {
    unsigned int b = __float_as_uint(v);
    b += 0x7fffu + ((b >> 16) & 1u);   // RNE
    return (unsigned short)(b >> 16);
}

// ---------------- node embedding: h = x @ node_w + node_b (fp32 + bf16 mirror) ----------------
__global__ void k_node_embed(const float* __restrict__ x, const float* __restrict__ nw,
                             const float* __restrict__ nb, float* __restrict__ h,
                             unsigned short* __restrict__ hb) {
    int idx = blockIdx.x * 256 + threadIdx.x;
    if (idx >= Nn * 128) return;
    int n = idx >> 7, c = idx & 127;
    const float* xr = x + (size_t)n * 8;
    float acc = nb[c];
#pragma unroll
    for (int k = 0; k < 8; k++) acc += xr[k] * nw[k * 128 + c];
    h[idx] = acc;
    hb[idx] = f2bf(acc);
}

// ---------------- small precompute: E1[128][8] = {M1[0..3][k], d1[k], 0,0,0} ----------------
__global__ void k_small(const float* __restrict__ vnfc, const float* __restrict__ vw,
                        const float* __restrict__ vb, const float* __restrict__ eab,
                        const float* __restrict__ a1w, const float* __restrict__ a1b,
                        const float* __restrict__ eaw, float* __restrict__ E1) {
    __shared__ float vr[128];
    __shared__ float sM1[512];
    __shared__ float sd1[128];
    int t = threadIdx.x;   // 512
    if (t < 128) {
        float a = vb[t];
#pragma unroll
        for (int k = 0; k < 6; k++) a += vnfc[k] * vw[k * 128 + t];
        vr[t] = a;
    }
    __syncthreads();
    if (t < 128) {
        float a = a1b[t];
        for (int k = 0; k < 128; k++) a += eab[k] * a1w[k * 128 + t];
        for (int k = 0; k < 128; k++) a += vr[k] * a1w[(128 + k) * 128 + t];
        sd1[t] = a;
    }
    {
        int r = t >> 7, j = t & 127;
        float a = 0.f;
        for (int k = 0; k < 128; k++) a += eaw[r * 128 + k] * a1w[k * 128 + j];
        sM1[r * 128 + j] = a;
    }
    __syncthreads();
    if (t < 128) {
        E1[t * 8 + 0] = sM1[t];
        E1[t * 8 + 1] = sM1[128 + t];
        E1[t * 8 + 2] = sM1[256 + t];
        E1[t * 8 + 3] = sM1[384 + t];
        E1[t * 8 + 4] = sd1[t];
        E1[t * 8 + 5] = 0.f; E1[t * 8 + 6] = 0.f; E1[t * 8 + 7] = 0.f;
    }
}

// ---------------- B matrices: Bs/Bd/Be [L][128][4] ----------------
__global__ void k_bmat(const float* __restrict__ glw, const float* __restrict__ gas,
                       const float* __restrict__ gad, const float* __restrict__ glew,
                       const float* __restrict__ gae, float* __restrict__ Bs,
                       float* __restrict__ Bd, float* __restrict__ Be) {
    int idx = blockIdx.x * 256 + threadIdx.x;
    if (idx >= LL * 128 * 4) return;
    int hh = idx & 3, k = (idx >> 2) & 127, l = idx >> 9;
    const float* lwp = glw  + (size_t)l * 65536 + k * 512 + hh * 128;
    const float* lep = glew + (size_t)l * 65536 + k * 512 + hh * 128;
    const float* sp = gas + l * 512 + hh * 128;
    const float* dp = gad + l * 512 + hh * 128;
    const float* ep = gae + l * 512 + hh * 128;
    float s1 = 0, s2 = 0, s3 = 0;
    for (int c = 0; c < 128; c++) {
        float lv = lwp[c];
        s1 += lv * sp[c];
        s2 += lv * dp[c];
        s3 += lep[c] * ep[c];
    }
    Bs[idx] = s1; Bd[idx] = s2; Be[idx] = s3;
}

// ---- glwT[l][col][k] bf16: col<512 = lw^T; 512..515 = Bs; 516..519 = Bd; 520..527 = 0 ----
__global__ void k_glwt(const float* __restrict__ glw, const float* __restrict__ Bs,
                       const float* __restrict__ Bd, unsigned short* __restrict__ glwT) {
    int idx = blockIdx.x * 256 + threadIdx.x;
    if (idx >= LL * 528 * 128) return;
    int k = idx & 127;
    int col = (idx >> 7) % 528;
    int l = idx / (528 * 128);
    float v;
    if (col < 512)      v = glw[(size_t)l * 65536 + k * 512 + col];
    else if (col < 516) v = Bs[l * 512 + k * 4 + (col - 512)];
    else if (col < 520) v = Bd[l * 512 + k * 4 + (col - 516)];
    else                v = 0.f;
    glwT[idx] = f2bf(v);
}

// ---------------- PB[4][24], cB[24]: fold ea_proj through Be ----------------
__global__ void k_pb(const float* __restrict__ eaw, const float* __restrict__ eab,
                     const float* __restrict__ Be, float* __restrict__ PB,
                     float* __restrict__ cB) {
    int t = threadIdx.x;
    if (t >= 24) return;
    int l = t >> 2, hh = t & 3;
    const float* bp = Be + l * 512 + hh;
    float s0 = 0, s1 = 0, s2 = 0, s3 = 0, sc = 0;
    for (int k = 0; k < 128; k++) {
        float bv = bp[k * 4];
        s0 += eaw[0 * 128 + k] * bv;
        s1 += eaw[1 * 128 + k] * bv;
        s2 += eaw[2 * 128 + k] * bv;
        s3 += eaw[3 * 128 + k] * bv;
        sc += eab[k] * bv;
    }
    PB[0 * 24 + t] = s0; PB[1 * 24 + t] = s1;
    PB[2 * 24 + t] = s2; PB[3 * 24 + t] = s3;
    cB[t] = sc;
}

// ---- edge gate MLP: LDS weights; 256 edges/block, 4/lane, packed-fp32 payload ----
__global__ __launch_bounds__(256) void k_edge(
    const float* __restrict__ ea, const float* __restrict__ E1,
    const float* __restrict__ a2w, const float* __restrict__ a2b,
    const float* __restrict__ a3w, const float* __restrict__ a3b,
    const float* __restrict__ PB, const float* __restrict__ cB,
    float* __restrict__ aleT, float* __restrict__ gsum) {
    __shared__ float sw2[128 * 64];   // 32 KB, [k][j]
    __shared__ float4 sM[128];
    __shared__ float sD[128];
    __shared__ float prs[4][256];
    __shared__ float gsh[256];
    int t = threadIdx.x;
    int lane = t & 63;
    int p = t >> 6;
    int ps = __builtin_amdgcn_readfirstlane(p);
    for (int z = t; z < 2048; z += 256) ((float4*)sw2)[z] = ((const float4*)a2w)[z];
    if (t < 128) { sM[t] = *(const float4*)(E1 + t * 8); sD[t] = E1[t * 8 + 4]; }
    __syncthreads();
    int eb = blockIdx.x * 256 + lane;
    float4 ev[4];
#pragma unroll
    for (int r = 0; r < 4; r++) ev[r] = *(const float4*)(ea + (size_t)(eb + r * 64) * 4);
    v2f acc[4][8];
#pragma unroll
    for (int j = 0; j < 8; j++) {
        v2f b = {a2b[ps * 16 + 2 * j], a2b[ps * 16 + 2 * j + 1]};
#pragma unroll
        for (int r = 0; r < 4; r++) acc[r][j] = b;
    }
    const float* w2base = sw2 + ps * 16;
    for (int k = 0; k < 128; k++) {
        float4 m = sM[k];
        float dk = sD[k];
        v2f xx[4];
#pragma unroll
        for (int r = 0; r < 4; r++) {
            float xv = fmaxf(dk + ev[r].x * m.x + ev[r].y * m.y + ev[r].z * m.z + ev[r].w * m.w, 0.f);
            xx[r][0] = xv; xx[r][1] = xv;
        }
        const float* w2r = w2base + k * 64;
#pragma unroll
        for (int j4 = 0; j4 < 4; j4++) {
            float4 wv = *(const float4*)(w2r + j4 * 4);
            v2f w01 = {wv.x, wv.y}, w23 = {wv.z, wv.w};
#pragma unroll
            for (int r = 0; r < 4; r++) {
                acc[r][2 * j4]     += xx[r] * w01;
                acc[r][2 * j4 + 1] += xx[r] * w23;
            }
        }
    }
#pragma unroll
    for (int r = 0; r < 4; r++) {
        float pr = 0.f;
#pragma unroll
        for (int j = 0; j < 8; j++) {
            pr += fmaxf(acc[r][j][0], 0.f) * a3w[ps * 16 + 2 * j];
            pr += fmaxf(acc[r][j][1], 0.f) * a3w[ps * 16 + 2 * j + 1];
        }
        prs[p][r * 64 + lane] = pr;
    }
    __syncthreads();
    if (p == 0) {
        float v0 = 0.f, v1 = 0.f, v2 = 0.f, v3 = 0.f, v4 = 0.f;
#pragma unroll
        for (int rep = 0; rep < 4; rep++) {
            int le = rep * 64 + lane;
            float tot = prs[0][le] + prs[1][le] + prs[2][le] + prs[3][le] + a3b[0];
            float g = 1.f / (1.f + __expf(-tot));
            gsh[le] = g;
            float4 evv = ev[rep];
            v0 += g; v1 += g * evv.x; v2 += g * evv.y; v3 += g * evv.z; v4 += g * evv.w;
        }
#pragma unroll
        for (int d = 32; d > 0; d >>= 1) {
            v0 += __shfl_down(v0, d); v1 += __shfl_down(v1, d); v2 += __shfl_down(v2, d);
            v3 += __shfl_down(v3, d); v4 += __shfl_down(v4, d);
        }
        if (lane == 0) {
            atomicAdd(&gsum[0], v0); atomicAdd(&gsum[1], v1); atomicAdd(&gsum[2], v2);
            atomicAdd(&gsum[3], v3); atomicAdd(&gsum[4], v4);
        }
    }
    __syncthreads();
#pragma unroll
    for (int rep = 0; rep < 2; rep++) {
        int i4 = (rep == 0) ? ps : (ps < 2 ? ps + 4 : -1);
        if (i4 >= 0) {
            float4 c  = *(const float4*)(cB + i4 * 4);
            float4 p0 = *(const float4*)(PB + 0 * 24 + i4 * 4);
            float4 p1 = *(const float4*)(PB + 1 * 24 + i4 * 4);
            float4 p2 = *(const float4*)(PB + 2 * 24 + i4 * 4);
            float4 p3 = *(const float4*)(PB + 3 * 24 + i4 * 4);
#pragma unroll
            for (int r = 0; r < 4; r++) {
                float g = gsh[r * 64 + lane];
                float4 evv = ev[r];
                float4 o;
                o.x = g * (c.x + evv.x * p0.x + evv.y * p1.x + evv.z * p2.x + evv.w * p3.x);
                o.y = g * (c.y + evv.x * p0.y + evv.y * p1.y + evv.z * p2.y + evv.w * p3.y);
                o.z = g * (c.z + evv.x * p0.z + evv.y * p1.z + evv.z * p2.z + evv.w * p3.z);
                o.w = g * (c.w + evv.x * p0.w + evv.y * p1.w + evv.z * p2.w + evv.w * p3.w);
                *(float4*)(aleT + (size_t)i4 * Ee * 4 + (size_t)(eb + r * 64) * 4) = o;
            }
        }
    }
}

// ---------------- loop-edge al_e from G,S sums ----------------
__global__ void k_lale(const float* __restrict__ gsum, const float* __restrict__ PB,
                       const float* __restrict__ cB, float* __restrict__ lale) {
    int t = threadIdx.x;
    if (t >= 24) return;
    float s = gsum[0] * cB[t] + gsum[1] * PB[t] + gsum[2] * PB[24 + t]
            + gsum[3] * PB[48 + t] + gsum[4] * PB[72 + t];
    lale[t] = s * (1.0f / Ee);
}

// ---------------- counting sort by dst: hist / scan / scatter ----------------
__global__ void k_hist(const int* __restrict__ ei, int* __restrict__ hist) {
    int i = blockIdx.x * 256 + threadIdx.x;
    if (i >= ET) return;
    int d = (i < Ee) ? ei[Ee + i] : (i - Ee);
    atomicAdd(&hist[d], 1);
}

__global__ __launch_bounds__(1024) void k_scan(const int* __restrict__ hist,
                                               int* __restrict__ seg, int* __restrict__ pos) {
    __shared__ int wsums[16];
    __shared__ int carry_s;
    int t = threadIdx.x;
    int lane = t & 63, wid = t >> 6;
    if (t == 0) { carry_s = 0; seg[0] = 0; }
    __syncthreads();
    for (int base = 0; base < Nn; base += 1024) {
        int idx = base + t;
        int v = (idx < Nn) ? hist[idx] : 0;
        int sc = v;
#pragma unroll
        for (int d = 1; d < 64; d <<= 1) {
            int up = __shfl_up(sc, d);
            if (lane >= d) sc += up;
        }
        if (lane == 63) wsums[wid] = sc;
        __syncthreads();
        if (wid == 0) {
            int wv = (lane < 16) ? wsums[lane] : 0;
            int wsc = wv;
#pragma unroll
            for (int d = 1; d < 16; d <<= 1) {
                int up = __shfl_up(wsc, d);
                if (lane >= d) wsc += up;
            }
            if (lane < 16) wsums[lane] = wsc - wv;
        }
        __syncthreads();
        int carry = carry_s;
        int inc = sc + wsums[wid] + carry;
        if (idx < Nn) { seg[idx + 1] = inc; pos[idx] = inc - v; }
        __syncthreads();
        if (t == 1023) carry_s = inc;
        __syncthreads();
    }
}

__global__ void k_scatter(const int* __restrict__ ei, int* __restrict__ pos,
                          int2* __restrict__ pse) {
    int i = blockIdx.x * 256 + threadIdx.x;
    if (i >= ET) return;
    int s, d;
    if (i < Ee) { s = ei[i]; d = ei[Ee + i]; } else { s = d = i - Ee; }
    int idx = atomicAdd(&pos[d], 1);
    pse[idx] = make_int2(s, i);
}

// ---- per-layer: xh(bf16) = hb @ glwT^T via MFMA; cols 512-519 give als/ald. No LDS. ----
__global__ __launch_bounds__(256) void k_xh_mfma(
    const unsigned short* __restrict__ hb, const unsigned short* __restrict__ glwT_l,
    unsigned short* __restrict__ xhb, float* __restrict__ als, float* __restrict__ ald) {
    int t = threadIdx.x;
    int lane = t & 63;
    int w = t >> 6;
    int n0 = blockIdx.x * 16;
    int m = lane & 15, q = lane >> 4;
    v8s fa[4];
    const unsigned short* arow = hb + (size_t)(n0 + m) * 128 + q * 8;
#pragma unroll
    for (int ks = 0; ks < 4; ks++) fa[ks] = *(const v8s*)(arow + ks * 32);
    int nt0 = w * 8;
#pragma unroll
    for (int nt = 0; nt < 8; nt++) {
        int col = (nt0 + nt) * 16 + m;
        const unsigned short* brow = glwT_l + (size_t)col * 128 + q * 8;
        v4f acc = {0.f, 0.f, 0.f, 0.f};
#pragma unroll
        for (int ks = 0; ks < 4; ks++) {
            v8s fb = *(const v8s*)(brow + ks * 32);
            acc = __builtin_amdgcn_mfma_f32_16x16x32_bf16(fa[ks], fb, acc, 0, 0, 0);
        }
#pragma unroll
        for (int r = 0; r < 4; r++)
            xhb[(size_t)(n0 + q * 4 + r) * 512 + col] = f2bf(acc[r]);
    }
    if (w == 3) {   // extra tile: cols 512..527 -> als (512..515), ald (516..519)
        int col = 512 + m;
        const unsigned short* brow = glwT_l + (size_t)col * 128 + q * 8;
        v4f acc = {0.f, 0.f, 0.f, 0.f};
#pragma unroll
        for (int ks = 0; ks < 4; ks++) {
            v8s fb = *(const v8s*)(brow + ks * 32);
            acc = __builtin_amdgcn_mfma_f32_16x16x32_bf16(fa[ks], fb, acc, 0, 0, 0);
        }
        if (m < 8) {
#pragma unroll
            for (int r = 0; r < 4; r++) {
                int row = n0 + q * 4 + r;
                if (m < 4) als[row * 4 + m] = acc[r];
                else       ald[row * 4 + (m - 4)] = acc[r];
            }
        }
    }
}

// ---- per-layer fused agg: 2 waves per node, 2 nodes/block; writes hio fp32 + hb bf16 ----
__global__ __launch_bounds__(256) void k_agg(
    const int2* __restrict__ pse, const int* __restrict__ seg,
    const float* __restrict__ als, const float* __restrict__ ald,
    const float* __restrict__ aleT_l, const float* __restrict__ lale_l,
    const unsigned short* __restrict__ xhb, const float* __restrict__ bias,
    const float* __restrict__ lnsc, const float* __restrict__ lnbi,
    float* __restrict__ hio, unsigned short* __restrict__ hb) {
    __shared__ float lgS[2][512];
    __shared__ int srcS[2][128];
    __shared__ float msS[2][2][8];
    __shared__ float part[2][128];
    int t = threadIdx.x;
    int lane = t & 63;
    int wv = (t >> 6) & 1;
    int w = t >> 7;
    int n = blockIdx.x * 2 + w;
    int start = seg[n], end = seg[n + 1];
    int deg = end - start;
    int half = (deg + 1) >> 1;
    int s0 = start + wv * half;
    int e0 = wv ? end : start + half;
    int h1 = lane & 3;
    float llh1 = lale_l[h1];
    float a1d = ald[n * 4 + h1];
    float m = -INFINITY, ss = 0.f;
    for (int i = s0 + (lane >> 2); i < e0; i += 16) {
        int idx = i - start;
        int2 se = pse[i];
        float alev = se.y < Ee ? aleT_l[(size_t)se.y * 4 + h1] : llh1;
        float av = als[se.x * 4 + h1] + a1d + alev;
        av = av > 0.f ? av : 0.2f * av;
        if (idx < 128) {
            lgS[w][idx * 4 + h1] = av;
            if (h1 == 0) srcS[w][idx] = se.x;
        }
        if (av > m) { ss = ss * __expf(m - av) + 1.f; m = av; }
        else ss += __expf(av - m);
    }
#pragma unroll
    for (int d = 4; d <= 32; d <<= 1) {
        float mo = __shfl_xor(m, d), so = __shfl_xor(ss, d);
        float mm = fmaxf(m, mo);
        float sv = 0.f;
        if (m > -INFINITY) sv += ss * __expf(m - mm);
        if (mo > -INFINITY) sv += so * __expf(mo - mm);
        m = mm; ss = sv;
    }
    if (lane < 4) { msS[w][wv][lane] = m; msS[w][wv][4 + lane] = ss; }
    __syncthreads();
    {
        float mo = msS[w][1 - wv][h1], so = msS[w][1 - wv][4 + h1];
        float mm = fmaxf(m, mo);
        float sv = 0.f;
        if (m > -INFINITY) sv += ss * __expf(m - mm);
        if (mo > -INFINITY) sv += so * __expf(mo - mm);
        m = mm; ss = sv;
    }
    float mh0 = __shfl(m, 0), mh1 = __shfl(m, 1), mh2 = __shfl(m, 2), mh3 = __shfl(m, 3);
    float iv0 = 1.f / (__shfl(ss, 0) + 1e-16f), iv1 = 1.f / (__shfl(ss, 1) + 1e-16f);
    float iv2 = 1.f / (__shfl(ss, 2) + 1e-16f), iv3 = 1.f / (__shfl(ss, 3) + 1e-16f);
    int lo = wv * half;
    int hi = min(wv ? deg : half, 128);
    for (int z = lo + lane; z < hi; z += 64) {
        float4 lg = *(float4*)&lgS[w][z * 4];
        lg.x = __expf(lg.x - mh0) * iv0;
        lg.y = __expf(lg.y - mh1) * iv1;
        lg.z = __expf(lg.z - mh2) * iv2;
        lg.w = __expf(lg.w - mh3) * iv3;
        *(float4*)&lgS[w][z * 4] = lg;
    }
    int hp = lane >> 4;
    int c8 = lane * 8;
    float4 acc0 = make_float4(0.f, 0.f, 0.f, 0.f);
    float4 acc1 = make_float4(0.f, 0.f, 0.f, 0.f);
    int i2 = lo;
    for (; i2 + 2 <= hi; i2 += 2) {
        int sa = srcS[w][i2], sb = srcS[w][i2 + 1];
        float wg0 = lgS[w][i2 * 4 + hp], wg1 = lgS[w][i2 * 4 + 4 + hp];
        uint4 u0 = *(const uint4*)(xhb + (size_t)sa * 512 + c8);
        uint4 u1 = *(const uint4*)(xhb + (size_t)sb * 512 + c8);
        acc0.x += wg0 * __uint_as_float(u0.x << 16) + wg1 * __uint_as_float(u1.x << 16);
        acc0.y += wg0 * __uint_as_float(u0.x & 0xffff0000u) + wg1 * __uint_as_float(u1.x & 0xffff0000u);
        acc0.z += wg0 * __uint_as_float(u0.y << 16) + wg1 * __uint_as_float(u1.y << 16);
        acc0.w += wg0 * __uint_as_float(u0.y & 0xffff0000u) + wg1 * __uint_as_float(u1.y & 0xffff0000u);
        acc1.x += wg0 * __uint_as_float(u0.z << 16) + wg1 * __uint_as_float(u1.z << 16);
        acc1.y += wg0 * __uint_as_float(u0.z & 0xffff0000u) + wg1 * __uint_as_float(u1.z & 0xffff0000u);
        acc1.z += wg0 * __uint_as_float(u0.w << 16) + wg1 * __uint_as_float(u1.w << 16);
        acc1.w += wg0 * __uint_as_float(u0.w & 0xffff0000u) + wg1 * __uint_as_float(u1.w & 0xffff0000u);
    }
    if (i2 < hi) {
        int sa = srcS[w][i2];
        float wg0 = lgS[w][i2 * 4 + hp];
        uint4 u0 = *(const uint4*)(xhb + (size_t)sa * 512 + c8);
        acc0.x += wg0 * __uint_as_float(u0.x << 16);
        acc0.y += wg0 * __uint_as_float(u0.x & 0xffff0000u);
        acc0.z += wg0 * __uint_as_float(u0.y << 16);
        acc0.w += wg0 * __uint_as_float(u0.y & 0xffff0000u);
        acc1.x += wg0 * __uint_as_float(u0.z << 16);
        acc1.y += wg0 * __uint_as_float(u0.z & 0xffff0000u);
        acc1.z += wg0 * __uint_as_float(u0.w << 16);
        acc1.w += wg0 * __uint_as_float(u0.w & 0xffff0000u);
    }
    float mhp = hp == 0 ? mh0 : hp == 1 ? mh1 : hp == 2 ? mh2 : mh3;
    float ivp = hp == 0 ? iv0 : hp == 1 ? iv1 : hp == 2 ? iv2 : iv3;
    for (int i = start + max(lo, 128); i < e0; i++) {
        int2 se = pse[i];
        float alev = se.y < Ee ? aleT_l[(size_t)se.y * 4 + hp] : lale_l[hp];
        float av = als[se.x * 4 + hp] + ald[n * 4 + hp] + alev;
        av = av > 0.f ? av : 0.2f * av;
        float wg0 = __expf(av - mhp) * ivp;
        uint4 u0 = *(const uint4*)(xhb + (size_t)se.x * 512 + c8);
        acc0.x += wg0 * __uint_as_float(u0.x << 16);
        acc0.y += wg0 * __uint_as_float(u0.x & 0xffff0000u);
        acc0.z += wg0 * __uint_as_float(u0.y << 16);
        acc0.w += wg0 * __uint_as_float(u0.y & 0xffff0000u);
        acc1.x += wg0 * __uint_as_float(u0.z << 16);
        acc1.y += wg0 * __uint_as_float(u0.z & 0xffff0000u);
        acc1.z += wg0 * __uint_as_float(u0.w << 16);
        acc1.w += wg0 * __uint_as_float(u0.w & 0xffff0000u);
    }
#pragma unroll
    for (int d = 16; d <= 32; d <<= 1) {
        acc0.x += __shfl_xor(acc0.x, d); acc0.y += __shfl_xor(acc0.y, d);
        acc0.z += __shfl_xor(acc0.z, d); acc0.w += __shfl_xor(acc0.w, d);
        acc1.x += __shfl_xor(acc1.x, d); acc1.y += __shfl_xor(acc1.y, d);
        acc1.z += __shfl_xor(acc1.z, d); acc1.w += __shfl_xor(acc1.w, d);
    }
    int cc = (lane & 15) * 8;
    if (wv == 1 && lane < 16) {
        *(float4*)&part[w][cc] = acc0;
        *(float4*)&part[w][cc + 4] = acc1;
    }
    __syncthreads();
    if (wv == 0) {
        float4 p0 = *(const float4*)&part[w][cc];
        float4 p1 = *(const float4*)&part[w][cc + 4];
        acc0.x += p0.x; acc0.y += p0.y; acc0.z += p0.z; acc0.w += p0.w;
        acc1.x += p1.x; acc1.y += p1.y; acc1.z += p1.z; acc1.w += p1.w;
        float4 b0 = *(const float4*)(bias + cc), b1 = *(const float4*)(bias + cc + 4);
        float4 h0 = *(const float4*)(hio + (size_t)n * 128 + cc);
        float4 h1v = *(const float4*)(hio + (size_t)n * 128 + cc + 4);
        float4 v0, v1;
        v0.x = h0.x + fmaxf(0.25f * acc0.x + b0.x, 0.f);
        v0.y = h0.y + fmaxf(0.25f * acc0.y + b0.y, 0.f);
        v0.z = h0.z + fmaxf(0.25f * acc0.z + b0.z, 0.f);
        v0.w = h0.w + fmaxf(0.25f * acc0.w + b0.w, 0.f);
        v1.x = h1v.x + fmaxf(0.25f * acc1.x + b1.x, 0.f);
        v1.y = h1v.y + fmaxf(0.25f * acc1.y + b1.y, 0.f);
        v1.z = h1v.z + fmaxf(0.25f * acc1.z + b1.z, 0.f);
        v1.w = h1v.w + fmaxf(0.25f * acc1.w + b1.w, 0.f);
        float s1 = v0.x + v0.y + v0.z + v0.w + v1.x + v1.y + v1.z + v1.w;
        float s2 = v0.x * v0.x + v0.y * v0.y + v0.z * v0.z + v0.w * v0.w
                 + v1.x * v1.x + v1.y * v1.y + v1.z * v1.z + v1.w * v1.w;
#pragma unroll
        for (int d = 1; d <= 8; d <<= 1) {
            s1 += __shfl_xor(s1, d); s2 += __shfl_xor(s2, d);
        }
        float mean = s1 * (1.f / 128.f);
        float var = s2 * (1.f / 128.f) - mean * mean;
        float rinv = rsqrtf(var + 1e-5f);
        if (lane < 16) {
            float4 ls0 = *(const float4*)(lnsc + cc), ls1 = *(const float4*)(lnsc + cc + 4);
            float4 lb0 = *(const float4*)(lnbi + cc), lb1 = *(const float4*)(lnbi + cc + 4);
            float4 o0, o1;
            o0.x = (v0.x - mean) * rinv * ls0.x + lb0.x;
            o0.y = (v0.y - mean) * rinv * ls0.y + lb0.y;
            o0.z = (v0.z - mean) * rinv * ls0.z + lb0.z;
            o0.w = (v0.w - mean) * rinv * ls0.w + lb0.w;
            o1.x = (v1.x - mean) * rinv * ls1.x + lb1.x;
            o1.y = (v1.y - mean) * rinv * ls1.y + lb1.y;
            o1.z = (v1.z - mean) * rinv * ls1.z + lb1.z;
            o1.w = (v1.w - mean) * rinv * ls1.w + lb1.w;
            *(float4*)(hio + (size_t)n * 128 + cc) = o0;
            *(float4*)(hio + (size_t)n * 128 + cc + 4) = o1;
            ushort4 q0, q1;
            q0.x = f2bf(o0.x); q0.y = f2bf(o0.y); q0.z = f2bf(o0.z); q0.w = f2bf(o0.w);
            q1.x = f2bf(o1.x); q1.y = f2bf(o1.y); q1.z = f2bf(o1.z); q1.w = f2bf(o1.w);
            *(ushort4*)(hb + (size_t)n * 128 + cc) = q0;
            *(ushort4*)(hb + (size_t)n * 128 + cc + 4) = q1;
        }
    }
}

// ---------------- output projection ----------------
__global__ __launch_bounds__(256) void k_out(
    const float* __restrict__ h, const float* __restrict__ ow,
    const float* __restrict__ ob, float* __restrict__ out) {
    __shared__ float4 hs4[8][32];
    int t = threadIdx.x;
    int n0 = blockIdx.x * 8;
    if (t < 256) {
        int i = t >> 5, kb = t & 31;
        hs4[i][kb] = *(const float4*)(h + (size_t)(n0 + i) * 128 + 4 * kb);
    }
    __syncthreads();
    float acc[8] = {0, 0, 0, 0, 0, 0, 0, 0};
    for (int kb = 0; kb < 32; kb++) {
        float w0 = ow[(4 * kb + 0) * 256 + t];
        float w1 = ow[(4 * kb + 1) * 256 + t];
        float w2 = ow[(4 * kb + 2) * 256 + t];
        float w3 = ow[(4 * kb + 3) * 256 + t];
#pragma unroll
        for (int i = 0; i < 8; i++) {
            float4 hv = hs4[i][kb];
            acc[i] += hv.x * w0 + hv.y * w1 + hv.z * w2 + hv.w * w3;
        }
    }
    float b = ob[t];
#pragma unroll
    for (int i = 0; i < 8; i++) out[(size_t)(n0 + i) * 256 + t] = acc[i] + b;
}

extern "C" void kernel_launch(void* const* d_in, const int* in_sizes, int n_in,
                              void* d_out, int out_size, void* d_ws, size_t ws_size,
                              hipStream_t stream) {
    const float* x    = (const float*)d_in[0];
    const int*   ei   = (const int*)d_in[1];
    const float* ea   = (const float*)d_in[2];
    const float* vnfc = (const float*)d_in[3];
    const float* nw   = (const float*)d_in[4];
    const float* nb   = (const float*)d_in[5];
    const float* eaw  = (const float*)d_in[6];
    const float* eab  = (const float*)d_in[7];
    const float* vw   = (const float*)d_in[8];
    const float* vb   = (const float*)d_in[9];
    const float* a1w  = (const float*)d_in[10];
    const float* a1b  = (const float*)d_in[11];
    const float* a2w  = (const float*)d_in[12];
    const float* a2b  = (const float*)d_in[13];
    const float* a3w  = (const float*)d_in[14];
    const float* a3b  = (const float*)d_in[15];
    const float* glw  = (const float*)d_in[16];
    const float* gas  = (const float*)d_in[17];
    const float* gad  = (const float*)d_in[18];
    const float* glew = (const float*)d_in[19];
    const float* gae  = (const float*)d_in[20];
    const float* gb   = (const float*)d_in[21];
    const float* lnsc = (const float*)d_in[22];
    const float* lnbi = (const float*)d_in[23];
    const float* ow   = (const float*)d_in[24];
    const float* ob   = (const float*)d_in[25];
    float* out = (float*)d_out;

    char* w = (char*)d_ws;
    size_t o = 0;
    auto allocf = [&](size_t cnt) { float* p = (float*)(w + o); o += ((cnt * 4 + 255) / 256) * 256; return p; };
    auto alloci = [&](size_t cnt) { int* p = (int*)(w + o); o += ((cnt * 4 + 255) / 256) * 256; return p; };
    auto allocu = [&](size_t cnt) { unsigned short* p = (unsigned short*)(w + o); o += ((cnt * 2 + 255) / 256) * 256; return p; };
    float* h      = allocf((size_t)Nn * 128);
    unsigned short* hb   = allocu((size_t)Nn * 128);
    unsigned short* xhb  = allocu((size_t)Nn * 512);
    unsigned short* glwT = allocu((size_t)LL * 528 * 128);
    float* als    = allocf((size_t)Nn * 4);
    float* ald    = allocf((size_t)Nn * 4);
    float* aleT   = allocf((size_t)LL * Ee * 4);
    float* Bs     = allocf(3072);
    float* Bd     = allocf(3072);
    float* Be     = allocf(3072);
    float* E1     = allocf(1024);
    float* PB     = allocf(96);
    float* cB     = allocf(24);
    float* gsum   = allocf(8);
    float* lale   = allocf(32);
    int* seg  = alloci(Nn + 1);
    int* hist = alloci(Nn);
    int* pos  = alloci(Nn);
    int2* pse = (int2*)alloci((size_t)ET * 2);

    hipMemsetAsync(hist, 0, Nn * sizeof(int), stream);
    hipMemsetAsync(gsum, 0, 8 * sizeof(float), stream);

    k_node_embed<<<(Nn * 128 + 255) / 256, 256, 0, stream>>>(x, nw, nb, h, hb);
    k_small<<<1, 512, 0, stream>>>(vnfc, vw, vb, eab, a1w, a1b, eaw, E1);
    k_bmat<<<(LL * 128 * 4 + 255) / 256, 256, 0, stream>>>(glw, gas, gad, glew, gae, Bs, Bd, Be);
    k_glwt<<<(LL * 528 * 128 + 255) / 256, 256, 0, stream>>>(glw, Bs, Bd, glwT);
    k_pb<<<1, 32, 0, stream>>>(eaw, eab, Be, PB, cB);
    k_edge<<<Ee / 256, 256, 0, stream>>>(ea, E1, a2w, a2b, a3w, a3b, PB, cB, aleT, gsum);
    k_hist<<<(ET + 255) / 256, 256, 0, stream>>>(ei, hist);
    k_scan<<<1, 1024, 0, stream>>>(hist, seg, pos);
    k_scatter<<<(ET + 255) / 256, 256, 0, stream>>>(ei, pos, pse);
    k_lale<<<1, 32, 0, stream>>>(gsum, PB, cB, lale);
    for (int l = 0; l < LL; l++) {
        k_xh_mfma<<<Nn / 16, 256, 0, stream>>>(hb, glwT + (size_t)l * 528 * 128, xhb, als, ald);
        k_agg<<<Nn / 2, 256, 0, stream>>>(pse, seg, als, ald, aleT + (size_t)l * Ee * 4,
                                          lale + l * 4, xhb,
                                          gb + l * 128, lnsc + l * 128, lnbi + l * 128, h, hb);
    }
    k_out<<<Nn / 8, 256, 0, stream>>>(h, ow, ob, out);
}